// Round 16
// baseline (391.158 us; speedup 1.0000x reference)
//
#include <hip/hip_runtime.h>
#include <cstdint>
#include <cstddef>

// ---------------- common types / helpers ----------------
typedef __attribute__((ext_vector_type(8))) short bf16x8;
typedef __attribute__((ext_vector_type(4))) float f32x4;
typedef __attribute__((ext_vector_type(16))) float f32x16;

#define S_LEN 2048
#define SCALE2 0.10411754f   // 192^-0.5 * log2(e)

__device__ __forceinline__ ushort f2bf(float f) {
  uint32_t u = __float_as_uint(f);
  u = (u + 0x7FFFu + ((u >> 16) & 1u)) >> 16;
  return (ushort)u;
}
__device__ __forceinline__ float bf2f(ushort u) {
  return __uint_as_float(((uint32_t)u) << 16);
}

typedef __attribute__((address_space(1))) void GV;
typedef __attribute__((address_space(3))) void LV;
__device__ __forceinline__ void gload16(const void* g, void* l) {
  __builtin_amdgcn_global_load_lds((GV*)g, (LV*)l, 16, 0, 0);
}

__device__ __forceinline__ void store_out(float* p, float v) { *p = v; }
__device__ __forceinline__ void store_out(ushort* p, float v) { *p = f2bf(v); }

// ---------------- fp32 -> bf16 convert ----------------
__global__ void k_f32_to_bf16(const float* __restrict__ in, ushort* __restrict__ out, int n4) {
  int i = blockIdx.x * blockDim.x + threadIdx.x;
  int stride = gridDim.x * blockDim.x;
  for (; i < n4; i += stride) {
    float4 v = reinterpret_cast<const float4*>(in)[i];
    ushort4 o;
    o.x = f2bf(v.x); o.y = f2bf(v.y); o.z = f2bf(v.z); o.w = f2bf(v.w);
    reinterpret_cast<ushort4*>(out)[i] = o;
  }
}

// ---------------- fp32 (R,C) -> bf16 transposed (C,R) ----------------
__global__ void k_transpose_f32_bf16(const float* __restrict__ in, ushort* __restrict__ out,
                                     int R, int C) {
  __shared__ float tile[32][33];
  int c0 = blockIdx.x * 32, r0 = blockIdx.y * 32;
  int tx = threadIdx.x, ty = threadIdx.y;
#pragma unroll
  for (int i = 0; i < 32; i += 8) {
    int r = r0 + ty + i, c = c0 + tx;
    if (r < R && c < C) tile[ty + i][tx] = in[(size_t)r * C + c];
  }
  __syncthreads();
#pragma unroll
  for (int i = 0; i < 32; i += 8) {
    int c = c0 + ty + i, r = r0 + tx;
    if (r < R && c < C) out[(size_t)c * R + r] = f2bf(tile[tx][ty + i]);
  }
}

// ---------------- 128x128 BK=64 bf16 GEMM, double-buffered (R4-proven schedule) ----------------
// R16 delta vs R15: double-buffer LDS + prefetch-issue of tile kt+1 BEFORE the
// compute of tile kt. Sync semantics identical to the R4-attn-proven pattern:
// every iteration ends with vmcnt(0)+lgkmcnt(0)+barrier (full drain, order-
// proof -- NOT the twice-failed counted-vmcnt protocol). The prefetched loads
// get the whole MFMA phase (~2000 cyc) to land, so the drain is near-free.
template <typename OUT>
__global__ __launch_bounds__(256) void k_gemm(const ushort* __restrict__ A,
                                              const ushort* __restrict__ Bt,
                                              OUT* __restrict__ C, int K, int Nreal) {
  __shared__ ushort As[2][128 * 72];   // 2 x 18432 B
  __shared__ ushort Bs[2][128 * 72];
  const int t = threadIdx.x, lane = t & 63, w = t >> 6;
  const int nwg = gridDim.x * gridDim.y;
  const int wg = blockIdx.y * gridDim.x + blockIdx.x;
  const int swz = (wg & 7) * (nwg >> 3) + (wg >> 3);
  const int m0 = (swz / gridDim.x) * 128, n0 = (swz % gridDim.x) * 128;
  const int wm = (w >> 1) * 64, wn = (w & 1) * 64;
  const int g = lane >> 4, q = lane & 15;
  const int nt = K >> 6;

  auto stage = [&](int kt, int p) {
#pragma unroll
    for (int it = 0; it < 5; ++it) {
      int ii = it * 4 + w;
      if (ii < 18) {
        unsigned s = ii * 64 + lane;         // 0..1151
        int r = s / 9, e = s - r * 9;        // r<128, e<9
        int cg = e ^ ((r >> 3) & 7);
        if (cg > 7) cg = 0;                  // pad slot -> dummy load
        gload16(A + (size_t)(m0 + r) * K + kt * 64 + cg * 8, (char*)&As[p][0] + ii * 1024);
        gload16(Bt + (size_t)(n0 + r) * K + kt * 64 + cg * 8, (char*)&Bs[p][0] + ii * 1024);
      }
    }
  };

  f32x4 acc[4][4] = {};
  stage(0, 0);
  asm volatile("s_waitcnt vmcnt(0)" ::: "memory");
  __syncthreads();

  for (int kt = 0; kt < nt; ++kt) {
    const int p = kt & 1;
    if (kt + 1 < nt) stage(kt + 1, p ^ 1);
#pragma unroll
    for (int kh = 0; kh < 2; ++kh) {
      bf16x8 af[4], bfr[4];
#pragma unroll
      for (int mi = 0; mi < 4; mi++) {
        int row = wm + 16 * mi + q;
        int rx = (row >> 3) & 7;
        af[mi] = *(const bf16x8*)(&As[p][0] + row * 72 + (((kh * 4 + g) ^ rx) << 3));
      }
#pragma unroll
      for (int ni = 0; ni < 4; ni++) {
        int row = wn + 16 * ni + q;
        int rx = (row >> 3) & 7;
        bfr[ni] = *(const bf16x8*)(&Bs[p][0] + row * 72 + (((kh * 4 + g) ^ rx) << 3));
      }
#pragma unroll
      for (int mi = 0; mi < 4; mi++)
#pragma unroll
        for (int ni = 0; ni < 4; ni++)
          acc[mi][ni] = __builtin_amdgcn_mfma_f32_16x16x32_bf16(af[mi], bfr[ni], acc[mi][ni], 0, 0, 0);
    }
    asm volatile("s_waitcnt vmcnt(0) lgkmcnt(0)" ::: "memory");
    __syncthreads();
  }

#pragma unroll
  for (int mi = 0; mi < 4; mi++)
#pragma unroll
    for (int ni = 0; ni < 4; ni++) {
      int col = n0 + wn + 16 * ni + q;
      if (col < Nreal) {
        int row = m0 + wm + 16 * mi + 4 * g;
#pragma unroll
        for (int r = 0; r < 4; r++)
          store_out(&C[(size_t)(row + r) * Nreal + col], acc[mi][ni][r]);
      }
    }
}

// ---------------- kv GEMM (BK=64, double-buffered): k_nope -> kbuf, V -> vT ----------------
__global__ __launch_bounds__(256) void k_gemm_kv(const ushort* __restrict__ A,
                                                 const ushort* __restrict__ Bt,
                                                 ushort* __restrict__ kbuf,
                                                 ushort* __restrict__ vT, int K) {
  __shared__ ushort As[2][128 * 72];
  __shared__ ushort Bs[2][128 * 72];
  const int t = threadIdx.x, lane = t & 63, w = t >> 6;
  const int nwg = gridDim.x * gridDim.y;
  const int wg = blockIdx.y * gridDim.x + blockIdx.x;
  const int swz = (wg & 7) * (nwg >> 3) + (wg >> 3);
  const int m0 = (swz / gridDim.x) * 128, n0 = (swz % gridDim.x) * 128;
  const int wm = (w >> 1) * 64, wn = (w & 1) * 64;
  const int g = lane >> 4, q = lane & 15;
  const int nt = K >> 6;

  auto stage = [&](int kt, int p) {
#pragma unroll
    for (int it = 0; it < 5; ++it) {
      int ii = it * 4 + w;
      if (ii < 18) {
        unsigned s = ii * 64 + lane;
        int r = s / 9, e = s - r * 9;
        int cg = e ^ ((r >> 3) & 7);
        if (cg > 7) cg = 0;
        gload16(A + (size_t)(m0 + r) * K + kt * 64 + cg * 8, (char*)&As[p][0] + ii * 1024);
        gload16(Bt + (size_t)(n0 + r) * K + kt * 64 + cg * 8, (char*)&Bs[p][0] + ii * 1024);
      }
    }
  };

  f32x4 acc[4][4] = {};
  stage(0, 0);
  asm volatile("s_waitcnt vmcnt(0)" ::: "memory");
  __syncthreads();

  for (int kt = 0; kt < nt; ++kt) {
    const int p = kt & 1;
    if (kt + 1 < nt) stage(kt + 1, p ^ 1);
#pragma unroll
    for (int kh = 0; kh < 2; ++kh) {
      bf16x8 af[4], bfr[4];
#pragma unroll
      for (int mi = 0; mi < 4; mi++) {
        int row = wm + 16 * mi + q;
        int rx = (row >> 3) & 7;
        af[mi] = *(const bf16x8*)(&As[p][0] + row * 72 + (((kh * 4 + g) ^ rx) << 3));
      }
#pragma unroll
      for (int ni = 0; ni < 4; ni++) {
        int row = wn + 16 * ni + q;
        int rx = (row >> 3) & 7;
        bfr[ni] = *(const bf16x8*)(&Bs[p][0] + row * 72 + (((kh * 4 + g) ^ rx) << 3));
      }
#pragma unroll
      for (int mi = 0; mi < 4; mi++)
#pragma unroll
        for (int ni = 0; ni < 4; ni++)
          acc[mi][ni] = __builtin_amdgcn_mfma_f32_16x16x32_bf16(af[mi], bfr[ni], acc[mi][ni], 0, 0, 0);
    }
    asm volatile("s_waitcnt vmcnt(0) lgkmcnt(0)" ::: "memory");
    __syncthreads();
  }

#pragma unroll
  for (int mi = 0; mi < 4; mi++)
#pragma unroll
    for (int ni = 0; ni < 4; ni++) {
      int col = n0 + wn + 16 * ni + q;     // 0..4095
      int hh = col >> 8, jj = col & 255;
      int row0 = m0 + wm + 16 * mi + 4 * g;
#pragma unroll
      for (int r = 0; r < 4; r++) {
        int tok = row0 + r;
        int bb = tok >> 11, ss = tok & 2047;
        ushort v = f2bf(acc[mi][ni][r]);
        if (jj < 128)
          kbuf[((size_t)(bb * 16 + hh) * 2048 + ss) * 192 + jj] = v;
        else
          vT[((size_t)(bb * 16 + hh) * 128 + (jj - 128)) * 2048 + ss] = v;
      }
    }
}

// ---------------- RMSNorm (fp32 in strided rows, bf16 out) ----------------
__global__ void k_rmsnorm_bf16(const float* __restrict__ in, const float* __restrict__ w,
                               ushort* __restrict__ out, int D, int instride) {
  int row = blockIdx.x;
  const float* x = in + (size_t)row * instride;
  ushort* o = out + (size_t)row * D;
  float ss = 0.f;
  for (int i = threadIdx.x; i < D; i += 256) { float v = x[i]; ss += v * v; }
#pragma unroll
  for (int m = 1; m < 64; m <<= 1) ss += __shfl_xor(ss, m);
  __shared__ float red[4];
  if ((threadIdx.x & 63) == 0) red[threadIdx.x >> 6] = ss;
  __syncthreads();
  float tot = red[0] + red[1] + red[2] + red[3];
  float sc = rsqrtf(tot / (float)D + 1e-6f);
  for (int i = threadIdx.x; i < D; i += 256) o[i] = f2bf(x[i] * sc * w[i]);
}

// ---------------- kv RMSNorm (512) + k_pe rope broadcast into kbuf ----------------
__global__ void k_kvnorm_rope(const float* __restrict__ cqkv, const float* __restrict__ w,
                              const float* __restrict__ cosT, const float* __restrict__ sinT,
                              ushort* __restrict__ ckvn, ushort* __restrict__ kbuf) {
  int tok = blockIdx.x, b = tok >> 11, s = tok & 2047;
  const float* x = cqkv + (size_t)tok * 2112 + 1536;
  float ss = 0.f;
  for (int i = threadIdx.x; i < 512; i += 256) { float v = x[i]; ss += v * v; }
#pragma unroll
  for (int m = 1; m < 64; m <<= 1) ss += __shfl_xor(ss, m);
  __shared__ float red[4];
  if ((threadIdx.x & 63) == 0) red[threadIdx.x >> 6] = ss;
  __syncthreads();
  float tot = red[0] + red[1] + red[2] + red[3];
  float sc = rsqrtf(tot / 512.f + 1e-6f);
  for (int i = threadIdx.x; i < 512; i += 256) ckvn[(size_t)tok * 512 + i] = f2bf(x[i] * sc * w[i]);
  if (threadIdx.x < 32) {
    int i = threadIdx.x;
    float xr = x[512 + 2 * i], xi = x[512 + 2 * i + 1];
    float c = cosT[s * 32 + i], sn = sinT[s * 32 + i];
    uint32_t lo = f2bf(xr * c - xi * sn);
    uint32_t hi = f2bf(xr * sn + xi * c);
    uint32_t pk = lo | (hi << 16);
#pragma unroll
    for (int h = 0; h < 16; ++h)
      *(uint32_t*)(kbuf + ((size_t)(b * 16 + h) * 2048 + s) * 192 + 128 + 2 * i) = pk;
  }
}

// ---------------- q rope, in-place on bf16 q (4096, 16, 192) ----------------
__global__ void k_qrope(ushort* __restrict__ qb, const float* __restrict__ cosT,
                        const float* __restrict__ sinT) {
  int tok = blockIdx.x, s = tok & (S_LEN - 1);
  for (int pp = threadIdx.x; pp < 512; pp += 256) {
    int h = pp >> 5, i = pp & 31;
    ushort* base = qb + ((size_t)tok * 16 + h) * 192 + 128;
    float xr = bf2f(base[2 * i]), xi = bf2f(base[2 * i + 1]);
    float c = cosT[s * 32 + i], sn = sinT[s * 32 + i];
    base[2 * i] = f2bf(xr * c - xi * sn);
    base[2 * i + 1] = f2bf(xr * sn + xi * c);
  }
}

// ---------------- causal flash attention (R14-proven: 112.4 us) ----------------
__global__ __launch_bounds__(256, 2) void k_attn10(const ushort* __restrict__ qb,
                                                   const ushort* __restrict__ kb,
                                                   const ushort* __restrict__ vT,
                                                   ushort* __restrict__ aout) {
  const int id = blockIdx.x;
  const int qt = 15 - (id >> 5);             // heavy-first (R7-proven mapping)
  const int bh = id & 31;
  const int h = bh & 15, b = bh >> 4;

  const int t = threadIdx.x, lane = t & 63, w = t >> 6;
  const int lq = lane & 31, hi = lane >> 5;
  const int kx = (lq >> 3) & 3;

  __shared__ ushort Ks[64 * 200];   // 25600 B
  __shared__ ushort Vs[128 * 72];   // 18432 B

  const ushort* kh = kb + (size_t)(b * 16 + h) * (2048 * 192);
  const ushort* vh = vT + (size_t)(b * 16 + h) * (128 * 2048);

  auto stage = [&](int k0) {
#pragma unroll
    for (int it = 0; it < 7; ++it) {
      int ii = it * 4 + w;
      if (ii < 25) {
        unsigned s = ii * 64 + lane;         // 0..1599
        int r = s / 25, e = s - r * 25;      // r<64, e<25 (e==24 pad)
        int cg = e ^ ((r >> 3) & 3);
        if (cg > 23) cg = 0;
        gload16(kh + (size_t)(k0 + r) * 192 + cg * 8, (char*)Ks + ii * 1024);
      }
    }
#pragma unroll
    for (int it = 0; it < 5; ++it) {
      int ii = it * 4 + w;
      if (ii < 18) {
        unsigned s = ii * 64 + lane;         // 0..1151
        int r = s / 9, e = s - r * 9;        // r<128, e<9 (e==8 pad)
        int cg = e ^ ((r >> 3) & 7);
        if (cg > 7) cg = 0;
        gload16(vh + (size_t)r * 2048 + k0 + cg * 8, (char*)Vs + ii * 1024);
      }
    }
  };

  const int q0 = qt * 128;
  const int q0w = q0 + 32 * w;
  const int qg = q0w + lq;
  const int nkt = qt * 2 + 2;

  bf16x8 qf[12];
  {
    const ushort* qp = qb + ((size_t)(b * 2048 + qg) * 16 + h) * 192 + 8 * hi;
#pragma unroll
    for (int s = 0; s < 12; ++s) qf[s] = *(const bf16x8*)(qp + 16 * s);
  }

  f32x16 oacc[4];
#pragma unroll
  for (int db = 0; db < 4; ++db)
#pragma unroll
    for (int r = 0; r < 16; ++r) oacc[db][r] = 0.f;
  float m = -1e30f, l = 0.f;

  for (int kt = 0; kt < nkt; ++kt) {
    const int k0 = kt * 64;
    stage(k0);
    asm volatile("s_waitcnt vmcnt(0)" ::: "memory");
    __syncthreads();
    if (k0 <= q0w + 31) {
      f32x16 sA, sB;
#pragma unroll
      for (int r = 0; r < 16; ++r) { sA[r] = 0.f; sB[r] = 0.f; }
      __builtin_amdgcn_s_setprio(1);
#pragma unroll
      for (int s = 0; s < 12; ++s) {
        int ch = ((2 * s + hi) ^ kx) << 3;
        bf16x8 kfA = *(const bf16x8*)(Ks + lq * 200 + ch);
        bf16x8 kfB = *(const bf16x8*)(Ks + (lq + 32) * 200 + ch);
        sA = __builtin_amdgcn_mfma_f32_32x32x16_bf16(kfA, qf[s], sA, 0, 0, 0);
        sB = __builtin_amdgcn_mfma_f32_32x32x16_bf16(kfB, qf[s], sB, 0, 0, 0);
      }
      __builtin_amdgcn_s_setprio(0);
      float svA[16], svB[16];
#pragma unroll
      for (int r = 0; r < 16; ++r) { svA[r] = sA[r]; svB[r] = sB[r]; }
      if (k0 + 63 > q0w) {
#pragma unroll
        for (int r = 0; r < 16; ++r) {
          int kk = (r & 3) + 8 * (r >> 2) + 4 * hi;
          if (k0 + kk > qg) svA[r] = -1e30f;
          if (k0 + 32 + kk > qg) svB[r] = -1e30f;
        }
      }
      float pmax = fmaxf(svA[0], svB[0]);
#pragma unroll
      for (int r = 1; r < 16; ++r) pmax = fmaxf(pmax, fmaxf(svA[r], svB[r]));
      pmax = fmaxf(pmax, __shfl_xor(pmax, 32));
      float smax = pmax * SCALE2;
      if (!__all(smax - m <= 8.0f)) {
        float mnew = fmaxf(m, smax);
        float a = exp2f(m - mnew);
        l *= a;
#pragma unroll
        for (int db = 0; db < 4; ++db)
#pragma unroll
          for (int r = 0; r < 16; ++r) oacc[db][r] *= a;
        m = mnew;
      }
      float eA[16], eB[16]; float sum = 0.f;
#pragma unroll
      for (int r = 0; r < 16; ++r) {
        eA[r] = exp2f(svA[r] * SCALE2 - m);
        eB[r] = exp2f(svB[r] * SCALE2 - m);
        sum += eA[r] + eB[r];
      }
      sum += __shfl_xor(sum, 32);
      l += sum;
      uint32_t pkA[8], pkB[8];
#pragma unroll
      for (int i = 0; i < 8; ++i) {
        pkA[i] = (uint32_t)f2bf(eA[2 * i]) | ((uint32_t)f2bf(eA[2 * i + 1]) << 16);
        pkB[i] = (uint32_t)f2bf(eB[2 * i]) | ((uint32_t)f2bf(eB[2 * i + 1]) << 16);
      }
      uint32_t swA[8], swB[8];
#pragma unroll
      for (int i = 0; i < 8; ++i) {
        swA[i] = (uint32_t)__shfl_xor((int)pkA[i], 32);
        swB[i] = (uint32_t)__shfl_xor((int)pkB[i], 32);
      }
      union { uint32_t u[4]; bf16x8 v; } pA0, pA1, pB0, pB1;
      pA0.u[0] = hi ? swA[2] : pkA[0];
      pA0.u[1] = hi ? swA[3] : pkA[1];
      pA0.u[2] = hi ? pkA[2] : swA[0];
      pA0.u[3] = hi ? pkA[3] : swA[1];
      pA1.u[0] = hi ? swA[6] : pkA[4];
      pA1.u[1] = hi ? swA[7] : pkA[5];
      pA1.u[2] = hi ? pkA[6] : swA[4];
      pA1.u[3] = hi ? pkA[7] : swA[5];
      pB0.u[0] = hi ? swB[2] : pkB[0];
      pB0.u[1] = hi ? swB[3] : pkB[1];
      pB0.u[2] = hi ? pkB[2] : swB[0];
      pB0.u[3] = hi ? pkB[3] : swB[1];
      pB1.u[0] = hi ? swB[6] : pkB[4];
      pB1.u[1] = hi ? swB[7] : pkB[5];
      pB1.u[2] = hi ? pkB[6] : swB[4];
      pB1.u[3] = hi ? pkB[7] : swB[5];
      __builtin_amdgcn_s_setprio(1);
#pragma unroll
      for (int db = 0; db < 4; ++db) {
        const int d = 32 * db + lq;
        const int vx = (d >> 3) & 7;
        const ushort* vr = Vs + d * 72;
        bf16x8 vf0 = *(const bf16x8*)(vr + (((0 + hi) ^ vx) << 3));
        bf16x8 vf1 = *(const bf16x8*)(vr + (((2 + hi) ^ vx) << 3));
        bf16x8 vf2 = *(const bf16x8*)(vr + (((4 + hi) ^ vx) << 3));
        bf16x8 vf3 = *(const bf16x8*)(vr + (((6 + hi) ^ vx) << 3));
        oacc[db] = __builtin_amdgcn_mfma_f32_32x32x16_bf16(vf0, pA0.v, oacc[db], 0, 0, 0);
        oacc[db] = __builtin_amdgcn_mfma_f32_32x32x16_bf16(vf1, pA1.v, oacc[db], 0, 0, 0);
        oacc[db] = __builtin_amdgcn_mfma_f32_32x32x16_bf16(vf2, pB0.v, oacc[db], 0, 0, 0);
        oacc[db] = __builtin_amdgcn_mfma_f32_32x32x16_bf16(vf3, pB1.v, oacc[db], 0, 0, 0);
      }
      __builtin_amdgcn_s_setprio(0);
    }
    asm volatile("s_waitcnt lgkmcnt(0)" ::: "memory");
    __syncthreads();
  }

  float inv = 1.f / l;
  ushort* op = aout + ((size_t)(b * 2048 + qg)) * 2048 + h * 128 + 4 * hi;
#pragma unroll
  for (int db = 0; db < 4; ++db)
#pragma unroll
    for (int i = 0; i < 8; ++i) {
      uint32_t u = (uint32_t)f2bf(oacc[db][2 * i] * inv) |
                   ((uint32_t)f2bf(oacc[db][2 * i + 1] * inv) << 16);
      int dbase = 32 * db + (i & 1) * 2 + (i >> 1) * 8;
      *(uint32_t*)(op + dbase) = u;
    }
}

// ---------------- launcher ----------------
extern "C" void kernel_launch(void* const* d_in, const int* in_sizes, int n_in,
                              void* d_out, int out_size, void* d_ws, size_t ws_size,
                              hipStream_t stream) {
  const float* x = (const float*)d_in[0];
  const float* fcos = (const float*)d_in[1];
  const float* fsin = (const float*)d_in[2];
  const float* wq_a = (const float*)d_in[3];
  const float* qnw = (const float*)d_in[4];
  const float* wq_b = (const float*)d_in[5];
  const float* wkv_a = (const float*)d_in[6];
  const float* kvnw = (const float*)d_in[7];
  const float* wkv_b = (const float*)d_in[8];
  const float* wo = (const float*)d_in[9];
  float* out = (float*)d_out;

  char* ws = (char*)d_ws;
  size_t off = 0;
  auto alloc = [&](size_t bytes) -> char* {
    char* p = ws + off;
    off += (bytes + 255) & ~(size_t)255;
    return p;
  };
  ushort* xb     = (ushort*)alloc(4096ull * 2048 * 2);
  ushort* wqkv_t = (ushort*)alloc(2176ull * 2048 * 2);   // rows 0-1535 wq_a^T, 1536-2111 wkv_a^T, rest pad
  ushort* wqb_t  = (ushort*)alloc(3072ull * 1536 * 2);
  ushort* wkvb_t = (ushort*)alloc(4096ull * 512 * 2);
  ushort* wo_t   = (ushort*)alloc(2048ull * 2048 * 2);
  float*  cqkv   = (float*)alloc(4096ull * 2112 * 4);    // fused q_lora | kv_lora | k_pe
  ushort* cqn    = (ushort*)alloc(4096ull * 1536 * 2);
  ushort* ckvn   = (ushort*)alloc(4096ull * 512 * 2);
  ushort* kbuf   = (ushort*)alloc(2ull * 16 * 2048 * 192 * 2);
  ushort* qbuf   = (ushort*)cqkv;   // reuse: cqkv dead after both norms
  ushort* aout   = xb;              // reuse: x dead after fused GEMM1
  ushort* vT     = wqkv_t;          // reuse: wqkv_t+wqb_t dead after GEMM2

  dim3 tb(32, 8);
  k_f32_to_bf16<<<2048, 256, 0, stream>>>(x, xb, 4096 * 2048 / 4);
  k_transpose_f32_bf16<<<dim3(48, 64), tb, 0, stream>>>(wq_a, wqkv_t, 2048, 1536);
  k_transpose_f32_bf16<<<dim3(18, 64), tb, 0, stream>>>(wkv_a, wqkv_t + 1536ull * 2048, 2048, 576);
  k_transpose_f32_bf16<<<dim3(96, 48), tb, 0, stream>>>(wq_b, wqb_t, 1536, 3072);
  k_transpose_f32_bf16<<<dim3(128, 16), tb, 0, stream>>>(wkv_b, wkvb_t, 512, 4096);
  k_transpose_f32_bf16<<<dim3(64, 64), tb, 0, stream>>>(wo, wo_t, 2048, 2048);

  // fused GEMM1: cqkv = xb @ [wq_a | wkv_a]  (M=4096, K=2048, Nreal=2112)
  k_gemm<float><<<dim3(17, 32), 256, 0, stream>>>(xb, wqkv_t, cqkv, 2048, 2112);

  k_rmsnorm_bf16<<<4096, 256, 0, stream>>>(cqkv, qnw, cqn, 1536, 2112);
  k_kvnorm_rope<<<4096, 256, 0, stream>>>(cqkv, kvnw, fcos, fsin, ckvn, kbuf);

  // q = cqn @ wq_b (K=1536, N=3072), bf16 out
  k_gemm<ushort><<<dim3(24, 32), 256, 0, stream>>>(cqn, wqb_t, qbuf, 1536, 3072);
  k_qrope<<<4096, 256, 0, stream>>>(qbuf, fcos, fsin);

  // kv = ckvn @ wkv_b (K=512, N=4096) -> kbuf + vT (scatter epilogue)
  k_gemm_kv<<<dim3(32, 32), 256, 0, stream>>>(ckvn, wkvb_t, kbuf, vT, 512);

  k_attn10<<<dim3(512), 256, 0, stream>>>(qbuf, kbuf, vT, aout);

  // out = aout @ wo (K=2048, N=2048), fp32 out
  k_gemm<float><<<dim3(16, 32), 256, 0, stream>>>(aout, wo_t, out, 2048, 2048);
}

// Round 17
// 354.244 us; speedup vs baseline: 1.1042x; 1.1042x over previous
//
#include <hip/hip_runtime.h>
#include <cstdint>
#include <cstddef>

// ---------------- common types / helpers ----------------
typedef __attribute__((ext_vector_type(8))) short bf16x8;
typedef __attribute__((ext_vector_type(4))) float f32x4;
typedef __attribute__((ext_vector_type(16))) float f32x16;

#define S_LEN 2048
#define SCALE2 0.10411754f   // 192^-0.5 * log2(e)

__device__ __forceinline__ ushort f2bf(float f) {
  uint32_t u = __float_as_uint(f);
  u = (u + 0x7FFFu + ((u >> 16) & 1u)) >> 16;
  return (ushort)u;
}
__device__ __forceinline__ float bf2f(ushort u) {
  return __uint_as_float(((uint32_t)u) << 16);
}

typedef __attribute__((address_space(1))) void GV;
typedef __attribute__((address_space(3))) void LV;
__device__ __forceinline__ void gload16(const void* g, void* l) {
  __builtin_amdgcn_global_load_lds((GV*)g, (LV*)l, 16, 0, 0);
}

__device__ __forceinline__ void store_out(float* p, float v) { *p = v; }
__device__ __forceinline__ void store_out(ushort* p, float v) { *p = f2bf(v); }

// ---------------- fp32 -> bf16 convert ----------------
__global__ void k_f32_to_bf16(const float* __restrict__ in, ushort* __restrict__ out, int n4) {
  int i = blockIdx.x * blockDim.x + threadIdx.x;
  int stride = gridDim.x * blockDim.x;
  for (; i < n4; i += stride) {
    float4 v = reinterpret_cast<const float4*>(in)[i];
    ushort4 o;
    o.x = f2bf(v.x); o.y = f2bf(v.y); o.z = f2bf(v.z); o.w = f2bf(v.w);
    reinterpret_cast<ushort4*>(out)[i] = o;
  }
}

// ---------------- fp32 (R,C) -> bf16 transposed (C,R) ----------------
__global__ void k_transpose_f32_bf16(const float* __restrict__ in, ushort* __restrict__ out,
                                     int R, int C) {
  __shared__ float tile[32][33];
  int c0 = blockIdx.x * 32, r0 = blockIdx.y * 32;
  int tx = threadIdx.x, ty = threadIdx.y;
#pragma unroll
  for (int i = 0; i < 32; i += 8) {
    int r = r0 + ty + i, c = c0 + tx;
    if (r < R && c < C) tile[ty + i][tx] = in[(size_t)r * C + c];
  }
  __syncthreads();
#pragma unroll
  for (int i = 0; i < 32; i += 8) {
    int c = c0 + ty + i, r = r0 + tx;
    if (r < R && c < C) out[(size_t)c * R + r] = f2bf(tile[tx][ty + i]);
  }
}

// ---------------- 128x128 BK=64 bf16 GEMM (R15-proven single-buffer form) ----------------
// R16's double-buffer prefetch REGRESSED (36->72KB LDS halved co-residency
// 4->2 blocks/CU; TLP loss > prefetch gain). This is the R15-proven engine.
template <typename OUT>
__global__ __launch_bounds__(256) void k_gemm(const ushort* __restrict__ A,
                                              const ushort* __restrict__ Bt,
                                              OUT* __restrict__ C, int K, int Nreal) {
  __shared__ ushort As[128 * 72];   // 18432 B
  __shared__ ushort Bs[128 * 72];   // 18432 B
  const int t = threadIdx.x, lane = t & 63, w = t >> 6;
  const int nwg = gridDim.x * gridDim.y;
  const int wg = blockIdx.y * gridDim.x + blockIdx.x;
  const int swz = (wg & 7) * (nwg >> 3) + (wg >> 3);
  const int m0 = (swz / gridDim.x) * 128, n0 = (swz % gridDim.x) * 128;
  const int wm = (w >> 1) * 64, wn = (w & 1) * 64;
  const int g = lane >> 4, q = lane & 15;
  f32x4 acc[4][4] = {};
  for (int kt = 0; kt < K; kt += 64) {
#pragma unroll
    for (int it = 0; it < 5; ++it) {
      int ii = it * 4 + w;
      if (ii < 18) {
        unsigned s = ii * 64 + lane;         // 0..1151
        int r = s / 9, e = s - r * 9;        // r<128, e<9
        int cg = e ^ ((r >> 3) & 7);
        if (cg > 7) cg = 0;                  // pad slot -> dummy load
        gload16(A + (size_t)(m0 + r) * K + kt + cg * 8, (char*)As + ii * 1024);
        gload16(Bt + (size_t)(n0 + r) * K + kt + cg * 8, (char*)Bs + ii * 1024);
      }
    }
    asm volatile("s_waitcnt vmcnt(0)" ::: "memory");
    __syncthreads();
#pragma unroll
    for (int kh = 0; kh < 2; ++kh) {
      bf16x8 af[4], bfr[4];
#pragma unroll
      for (int mi = 0; mi < 4; mi++) {
        int row = wm + 16 * mi + q;
        int rx = (row >> 3) & 7;
        af[mi] = *(const bf16x8*)(As + row * 72 + (((kh * 4 + g) ^ rx) << 3));
      }
#pragma unroll
      for (int ni = 0; ni < 4; ni++) {
        int row = wn + 16 * ni + q;
        int rx = (row >> 3) & 7;
        bfr[ni] = *(const bf16x8*)(Bs + row * 72 + (((kh * 4 + g) ^ rx) << 3));
      }
#pragma unroll
      for (int mi = 0; mi < 4; mi++)
#pragma unroll
        for (int ni = 0; ni < 4; ni++)
          acc[mi][ni] = __builtin_amdgcn_mfma_f32_16x16x32_bf16(af[mi], bfr[ni], acc[mi][ni], 0, 0, 0);
    }
    __syncthreads();
  }
#pragma unroll
  for (int mi = 0; mi < 4; mi++)
#pragma unroll
    for (int ni = 0; ni < 4; ni++) {
      int col = n0 + wn + 16 * ni + q;
      if (col < Nreal) {
        int row = m0 + wm + 16 * mi + 4 * g;
#pragma unroll
        for (int r = 0; r < 4; r++)
          store_out(&C[(size_t)(row + r) * Nreal + col], acc[mi][ni][r]);
      }
    }
}

// ---------------- GEMM2 variant: q projection with FUSED RoPE epilogue ----------------
// Identical main loop to k_gemm (R15 bytes). Epilogue: output layout is
// (tok, 16 heads, 192); head-offset hoff = col % 192. Each wave's 16-col span
// is 16-aligned inside one head -> rope/nope branch is WAVE-UNIFORM (hoff
// region boundary at 128 is a multiple of 16). Rope pairs (128+2i, 128+2i+1)
// live in lanes q and q^1 -> one shfl_xor(v,1) exchanges them. Even lane
// computes yr = v*c - p*sn; odd lane yi = p*sn + v*c. Eliminates the separate
// k_qrope pass (~75 MB traffic).
__global__ __launch_bounds__(256) void k_gemm_qrope(const ushort* __restrict__ A,
                                                    const ushort* __restrict__ Bt,
                                                    ushort* __restrict__ C, int K,
                                                    const float* __restrict__ cosT,
                                                    const float* __restrict__ sinT) {
  __shared__ ushort As[128 * 72];
  __shared__ ushort Bs[128 * 72];
  const int t = threadIdx.x, lane = t & 63, w = t >> 6;
  const int nwg = gridDim.x * gridDim.y;
  const int wg = blockIdx.y * gridDim.x + blockIdx.x;
  const int swz = (wg & 7) * (nwg >> 3) + (wg >> 3);
  const int m0 = (swz / gridDim.x) * 128, n0 = (swz % gridDim.x) * 128;
  const int wm = (w >> 1) * 64, wn = (w & 1) * 64;
  const int g = lane >> 4, q = lane & 15;
  f32x4 acc[4][4] = {};
  for (int kt = 0; kt < K; kt += 64) {
#pragma unroll
    for (int it = 0; it < 5; ++it) {
      int ii = it * 4 + w;
      if (ii < 18) {
        unsigned s = ii * 64 + lane;
        int r = s / 9, e = s - r * 9;
        int cg = e ^ ((r >> 3) & 7);
        if (cg > 7) cg = 0;
        gload16(A + (size_t)(m0 + r) * K + kt + cg * 8, (char*)As + ii * 1024);
        gload16(Bt + (size_t)(n0 + r) * K + kt + cg * 8, (char*)Bs + ii * 1024);
      }
    }
    asm volatile("s_waitcnt vmcnt(0)" ::: "memory");
    __syncthreads();
#pragma unroll
    for (int kh = 0; kh < 2; ++kh) {
      bf16x8 af[4], bfr[4];
#pragma unroll
      for (int mi = 0; mi < 4; mi++) {
        int row = wm + 16 * mi + q;
        int rx = (row >> 3) & 7;
        af[mi] = *(const bf16x8*)(As + row * 72 + (((kh * 4 + g) ^ rx) << 3));
      }
#pragma unroll
      for (int ni = 0; ni < 4; ni++) {
        int row = wn + 16 * ni + q;
        int rx = (row >> 3) & 7;
        bfr[ni] = *(const bf16x8*)(Bs + row * 72 + (((kh * 4 + g) ^ rx) << 3));
      }
#pragma unroll
      for (int mi = 0; mi < 4; mi++)
#pragma unroll
        for (int ni = 0; ni < 4; ni++)
          acc[mi][ni] = __builtin_amdgcn_mfma_f32_16x16x32_bf16(af[mi], bfr[ni], acc[mi][ni], 0, 0, 0);
    }
    __syncthreads();
  }
#pragma unroll
  for (int mi = 0; mi < 4; mi++)
#pragma unroll
    for (int ni = 0; ni < 4; ni++) {
      int col = n0 + wn + 16 * ni + q;       // < 3072 always (grid exact)
      int hoff = col % 192;
      int row = m0 + wm + 16 * mi + 4 * g;
      if (hoff < 128) {                      // wave-uniform branch
#pragma unroll
        for (int r = 0; r < 4; r++)
          C[(size_t)(row + r) * 3072 + col] = f2bf(acc[mi][ni][r]);
      } else {
        int i = (hoff - 128) >> 1;           // pair index; same for lanes q,q^1
#pragma unroll
        for (int r = 0; r < 4; r++) {
          int s2 = (row + r) & 2047;
          float c = cosT[s2 * 32 + i], sn = sinT[s2 * 32 + i];
          float v = acc[mi][ni][r];
          float p = __shfl_xor(v, 1);        // partner column's value
          float res = (q & 1) ? (p * sn + v * c) : (v * c - p * sn);
          C[(size_t)(row + r) * 3072 + col] = f2bf(res);
        }
      }
    }
}

// ---------------- kv GEMM (R15-proven single-buffer form): k_nope -> kbuf, V -> vT ----------------
__global__ __launch_bounds__(256) void k_gemm_kv(const ushort* __restrict__ A,
                                                 const ushort* __restrict__ Bt,
                                                 ushort* __restrict__ kbuf,
                                                 ushort* __restrict__ vT, int K) {
  __shared__ ushort As[128 * 72];
  __shared__ ushort Bs[128 * 72];
  const int t = threadIdx.x, lane = t & 63, w = t >> 6;
  const int nwg = gridDim.x * gridDim.y;
  const int wg = blockIdx.y * gridDim.x + blockIdx.x;
  const int swz = (wg & 7) * (nwg >> 3) + (wg >> 3);
  const int m0 = (swz / gridDim.x) * 128, n0 = (swz % gridDim.x) * 128;
  const int wm = (w >> 1) * 64, wn = (w & 1) * 64;
  const int g = lane >> 4, q = lane & 15;
  f32x4 acc[4][4] = {};
  for (int kt = 0; kt < K; kt += 64) {
#pragma unroll
    for (int it = 0; it < 5; ++it) {
      int ii = it * 4 + w;
      if (ii < 18) {
        unsigned s = ii * 64 + lane;
        int r = s / 9, e = s - r * 9;
        int cg = e ^ ((r >> 3) & 7);
        if (cg > 7) cg = 0;
        gload16(A + (size_t)(m0 + r) * K + kt + cg * 8, (char*)As + ii * 1024);
        gload16(Bt + (size_t)(n0 + r) * K + kt + cg * 8, (char*)Bs + ii * 1024);
      }
    }
    asm volatile("s_waitcnt vmcnt(0)" ::: "memory");
    __syncthreads();
#pragma unroll
    for (int kh = 0; kh < 2; ++kh) {
      bf16x8 af[4], bfr[4];
#pragma unroll
      for (int mi = 0; mi < 4; mi++) {
        int row = wm + 16 * mi + q;
        int rx = (row >> 3) & 7;
        af[mi] = *(const bf16x8*)(As + row * 72 + (((kh * 4 + g) ^ rx) << 3));
      }
#pragma unroll
      for (int ni = 0; ni < 4; ni++) {
        int row = wn + 16 * ni + q;
        int rx = (row >> 3) & 7;
        bfr[ni] = *(const bf16x8*)(Bs + row * 72 + (((kh * 4 + g) ^ rx) << 3));
      }
#pragma unroll
      for (int mi = 0; mi < 4; mi++)
#pragma unroll
        for (int ni = 0; ni < 4; ni++)
          acc[mi][ni] = __builtin_amdgcn_mfma_f32_16x16x32_bf16(af[mi], bfr[ni], acc[mi][ni], 0, 0, 0);
    }
    __syncthreads();
  }
#pragma unroll
  for (int mi = 0; mi < 4; mi++)
#pragma unroll
    for (int ni = 0; ni < 4; ni++) {
      int col = n0 + wn + 16 * ni + q;     // 0..4095
      int hh = col >> 8, jj = col & 255;
      int row0 = m0 + wm + 16 * mi + 4 * g;
#pragma unroll
      for (int r = 0; r < 4; r++) {
        int tok = row0 + r;
        int bb = tok >> 11, ss = tok & 2047;
        ushort v = f2bf(acc[mi][ni][r]);
        if (jj < 128)
          kbuf[((size_t)(bb * 16 + hh) * 2048 + ss) * 192 + jj] = v;
        else
          vT[((size_t)(bb * 16 + hh) * 128 + (jj - 128)) * 2048 + ss] = v;
      }
    }
}

// ---------------- RMSNorm (fp32 in strided rows, bf16 out) ----------------
__global__ void k_rmsnorm_bf16(const float* __restrict__ in, const float* __restrict__ w,
                               ushort* __restrict__ out, int D, int instride) {
  int row = blockIdx.x;
  const float* x = in + (size_t)row * instride;
  ushort* o = out + (size_t)row * D;
  float ss = 0.f;
  for (int i = threadIdx.x; i < D; i += 256) { float v = x[i]; ss += v * v; }
#pragma unroll
  for (int m = 1; m < 64; m <<= 1) ss += __shfl_xor(ss, m);
  __shared__ float red[4];
  if ((threadIdx.x & 63) == 0) red[threadIdx.x >> 6] = ss;
  __syncthreads();
  float tot = red[0] + red[1] + red[2] + red[3];
  float sc = rsqrtf(tot / (float)D + 1e-6f);
  for (int i = threadIdx.x; i < D; i += 256) o[i] = f2bf(x[i] * sc * w[i]);
}

// ---------------- kv RMSNorm (512) + k_pe rope broadcast into kbuf ----------------
__global__ void k_kvnorm_rope(const float* __restrict__ cqkv, const float* __restrict__ w,
                              const float* __restrict__ cosT, const float* __restrict__ sinT,
                              ushort* __restrict__ ckvn, ushort* __restrict__ kbuf) {
  int tok = blockIdx.x, b = tok >> 11, s = tok & 2047;
  const float* x = cqkv + (size_t)tok * 2112 + 1536;
  float ss = 0.f;
  for (int i = threadIdx.x; i < 512; i += 256) { float v = x[i]; ss += v * v; }
#pragma unroll
  for (int m = 1; m < 64; m <<= 1) ss += __shfl_xor(ss, m);
  __shared__ float red[4];
  if ((threadIdx.x & 63) == 0) red[threadIdx.x >> 6] = ss;
  __syncthreads();
  float tot = red[0] + red[1] + red[2] + red[3];
  float sc = rsqrtf(tot / 512.f + 1e-6f);
  for (int i = threadIdx.x; i < 512; i += 256) ckvn[(size_t)tok * 512 + i] = f2bf(x[i] * sc * w[i]);
  if (threadIdx.x < 32) {
    int i = threadIdx.x;
    float xr = x[512 + 2 * i], xi = x[512 + 2 * i + 1];
    float c = cosT[s * 32 + i], sn = sinT[s * 32 + i];
    uint32_t lo = f2bf(xr * c - xi * sn);
    uint32_t hi = f2bf(xr * sn + xi * c);
    uint32_t pk = lo | (hi << 16);
#pragma unroll
    for (int h = 0; h < 16; ++h)
      *(uint32_t*)(kbuf + ((size_t)(b * 16 + h) * 2048 + s) * 192 + 128 + 2 * i) = pk;
  }
}

// ---------------- causal flash attention (R14-proven: 112.4 us) ----------------
__global__ __launch_bounds__(256, 2) void k_attn10(const ushort* __restrict__ qb,
                                                   const ushort* __restrict__ kb,
                                                   const ushort* __restrict__ vT,
                                                   ushort* __restrict__ aout) {
  const int id = blockIdx.x;
  const int qt = 15 - (id >> 5);             // heavy-first (R7-proven mapping)
  const int bh = id & 31;
  const int h = bh & 15, b = bh >> 4;

  const int t = threadIdx.x, lane = t & 63, w = t >> 6;
  const int lq = lane & 31, hi = lane >> 5;
  const int kx = (lq >> 3) & 3;

  __shared__ ushort Ks[64 * 200];   // 25600 B
  __shared__ ushort Vs[128 * 72];   // 18432 B

  const ushort* kh = kb + (size_t)(b * 16 + h) * (2048 * 192);
  const ushort* vh = vT + (size_t)(b * 16 + h) * (128 * 2048);

  auto stage = [&](int k0) {
#pragma unroll
    for (int it = 0; it < 7; ++it) {
      int ii = it * 4 + w;
      if (ii < 25) {
        unsigned s = ii * 64 + lane;         // 0..1599
        int r = s / 25, e = s - r * 25;      // r<64, e<25 (e==24 pad)
        int cg = e ^ ((r >> 3) & 3);
        if (cg > 23) cg = 0;
        gload16(kh + (size_t)(k0 + r) * 192 + cg * 8, (char*)Ks + ii * 1024);
      }
    }
#pragma unroll
    for (int it = 0; it < 5; ++it) {
      int ii = it * 4 + w;
      if (ii < 18) {
        unsigned s = ii * 64 + lane;         // 0..1151
        int r = s / 9, e = s - r * 9;        // r<128, e<9 (e==8 pad)
        int cg = e ^ ((r >> 3) & 7);
        if (cg > 7) cg = 0;
        gload16(vh + (size_t)r * 2048 + k0 + cg * 8, (char*)Vs + ii * 1024);
      }
    }
  };

  const int q0 = qt * 128;
  const int q0w = q0 + 32 * w;
  const int qg = q0w + lq;
  const int nkt = qt * 2 + 2;

  bf16x8 qf[12];
  {
    const ushort* qp = qb + ((size_t)(b * 2048 + qg) * 16 + h) * 192 + 8 * hi;
#pragma unroll
    for (int s = 0; s < 12; ++s) qf[s] = *(const bf16x8*)(qp + 16 * s);
  }

  f32x16 oacc[4];
#pragma unroll
  for (int db = 0; db < 4; ++db)
#pragma unroll
    for (int r = 0; r < 16; ++r) oacc[db][r] = 0.f;
  float m = -1e30f, l = 0.f;

  for (int kt = 0; kt < nkt; ++kt) {
    const int k0 = kt * 64;
    stage(k0);
    asm volatile("s_waitcnt vmcnt(0)" ::: "memory");
    __syncthreads();
    if (k0 <= q0w + 31) {
      f32x16 sA, sB;
#pragma unroll
      for (int r = 0; r < 16; ++r) { sA[r] = 0.f; sB[r] = 0.f; }
      __builtin_amdgcn_s_setprio(1);
#pragma unroll
      for (int s = 0; s < 12; ++s) {
        int ch = ((2 * s + hi) ^ kx) << 3;
        bf16x8 kfA = *(const bf16x8*)(Ks + lq * 200 + ch);
        bf16x8 kfB = *(const bf16x8*)(Ks + (lq + 32) * 200 + ch);
        sA = __builtin_amdgcn_mfma_f32_32x32x16_bf16(kfA, qf[s], sA, 0, 0, 0);
        sB = __builtin_amdgcn_mfma_f32_32x32x16_bf16(kfB, qf[s], sB, 0, 0, 0);
      }
      __builtin_amdgcn_s_setprio(0);
      float svA[16], svB[16];
#pragma unroll
      for (int r = 0; r < 16; ++r) { svA[r] = sA[r]; svB[r] = sB[r]; }
      if (k0 + 63 > q0w) {
#pragma unroll
        for (int r = 0; r < 16; ++r) {
          int kk = (r & 3) + 8 * (r >> 2) + 4 * hi;
          if (k0 + kk > qg) svA[r] = -1e30f;
          if (k0 + 32 + kk > qg) svB[r] = -1e30f;
        }
      }
      float pmax = fmaxf(svA[0], svB[0]);
#pragma unroll
      for (int r = 1; r < 16; ++r) pmax = fmaxf(pmax, fmaxf(svA[r], svB[r]));
      pmax = fmaxf(pmax, __shfl_xor(pmax, 32));
      float smax = pmax * SCALE2;
      if (!__all(smax - m <= 8.0f)) {
        float mnew = fmaxf(m, smax);
        float a = exp2f(m - mnew);
        l *= a;
#pragma unroll
        for (int db = 0; db < 4; ++db)
#pragma unroll
          for (int r = 0; r < 16; ++r) oacc[db][r] *= a;
        m = mnew;
      }
      float eA[16], eB[16]; float sum = 0.f;
#pragma unroll
      for (int r = 0; r < 16; ++r) {
        eA[r] = exp2f(svA[r] * SCALE2 - m);
        eB[r] = exp2f(svB[r] * SCALE2 - m);
        sum += eA[r] + eB[r];
      }
      sum += __shfl_xor(sum, 32);
      l += sum;
      uint32_t pkA[8], pkB[8];
#pragma unroll
      for (int i = 0; i < 8; ++i) {
        pkA[i] = (uint32_t)f2bf(eA[2 * i]) | ((uint32_t)f2bf(eA[2 * i + 1]) << 16);
        pkB[i] = (uint32_t)f2bf(eB[2 * i]) | ((uint32_t)f2bf(eB[2 * i + 1]) << 16);
      }
      uint32_t swA[8], swB[8];
#pragma unroll
      for (int i = 0; i < 8; ++i) {
        swA[i] = (uint32_t)__shfl_xor((int)pkA[i], 32);
        swB[i] = (uint32_t)__shfl_xor((int)pkB[i], 32);
      }
      union { uint32_t u[4]; bf16x8 v; } pA0, pA1, pB0, pB1;
      pA0.u[0] = hi ? swA[2] : pkA[0];
      pA0.u[1] = hi ? swA[3] : pkA[1];
      pA0.u[2] = hi ? pkA[2] : swA[0];
      pA0.u[3] = hi ? pkA[3] : swA[1];
      pA1.u[0] = hi ? swA[6] : pkA[4];
      pA1.u[1] = hi ? swA[7] : pkA[5];
      pA1.u[2] = hi ? pkA[6] : swA[4];
      pA1.u[3] = hi ? pkA[7] : swA[5];
      pB0.u[0] = hi ? swB[2] : pkB[0];
      pB0.u[1] = hi ? swB[3] : pkB[1];
      pB0.u[2] = hi ? pkB[2] : swB[0];
      pB0.u[3] = hi ? pkB[3] : swB[1];
      pB1.u[0] = hi ? swB[6] : pkB[4];
      pB1.u[1] = hi ? swB[7] : pkB[5];
      pB1.u[2] = hi ? pkB[6] : swB[4];
      pB1.u[3] = hi ? pkB[7] : swB[5];
      __builtin_amdgcn_s_setprio(1);
#pragma unroll
      for (int db = 0; db < 4; ++db) {
        const int d = 32 * db + lq;
        const int vx = (d >> 3) & 7;
        const ushort* vr = Vs + d * 72;
        bf16x8 vf0 = *(const bf16x8*)(vr + (((0 + hi) ^ vx) << 3));
        bf16x8 vf1 = *(const bf16x8*)(vr + (((2 + hi) ^ vx) << 3));
        bf16x8 vf2 = *(const bf16x8*)(vr + (((4 + hi) ^ vx) << 3));
        bf16x8 vf3 = *(const bf16x8*)(vr + (((6 + hi) ^ vx) << 3));
        oacc[db] = __builtin_amdgcn_mfma_f32_32x32x16_bf16(vf0, pA0.v, oacc[db], 0, 0, 0);
        oacc[db] = __builtin_amdgcn_mfma_f32_32x32x16_bf16(vf1, pA1.v, oacc[db], 0, 0, 0);
        oacc[db] = __builtin_amdgcn_mfma_f32_32x32x16_bf16(vf2, pB0.v, oacc[db], 0, 0, 0);
        oacc[db] = __builtin_amdgcn_mfma_f32_32x32x16_bf16(vf3, pB1.v, oacc[db], 0, 0, 0);
      }
      __builtin_amdgcn_s_setprio(0);
    }
    asm volatile("s_waitcnt lgkmcnt(0)" ::: "memory");
    __syncthreads();
  }

  float inv = 1.f / l;
  ushort* op = aout + ((size_t)(b * 2048 + qg)) * 2048 + h * 128 + 4 * hi;
#pragma unroll
  for (int db = 0; db < 4; ++db)
#pragma unroll
    for (int i = 0; i < 8; ++i) {
      uint32_t u = (uint32_t)f2bf(oacc[db][2 * i] * inv) |
                   ((uint32_t)f2bf(oacc[db][2 * i + 1] * inv) << 16);
      int dbase = 32 * db + (i & 1) * 2 + (i >> 1) * 8;
      *(uint32_t*)(op + dbase) = u;
    }
}

// ---------------- launcher ----------------
extern "C" void kernel_launch(void* const* d_in, const int* in_sizes, int n_in,
                              void* d_out, int out_size, void* d_ws, size_t ws_size,
                              hipStream_t stream) {
  const float* x = (const float*)d_in[0];
  const float* fcos = (const float*)d_in[1];
  const float* fsin = (const float*)d_in[2];
  const float* wq_a = (const float*)d_in[3];
  const float* qnw = (const float*)d_in[4];
  const float* wq_b = (const float*)d_in[5];
  const float* wkv_a = (const float*)d_in[6];
  const float* kvnw = (const float*)d_in[7];
  const float* wkv_b = (const float*)d_in[8];
  const float* wo = (const float*)d_in[9];
  float* out = (float*)d_out;

  char* ws = (char*)d_ws;
  size_t off = 0;
  auto alloc = [&](size_t bytes) -> char* {
    char* p = ws + off;
    off += (bytes + 255) & ~(size_t)255;
    return p;
  };
  ushort* xb     = (ushort*)alloc(4096ull * 2048 * 2);
  ushort* wqkv_t = (ushort*)alloc(2176ull * 2048 * 2);   // rows 0-1535 wq_a^T, 1536-2111 wkv_a^T, rest pad
  ushort* wqb_t  = (ushort*)alloc(3072ull * 1536 * 2);
  ushort* wkvb_t = (ushort*)alloc(4096ull * 512 * 2);
  ushort* wo_t   = (ushort*)alloc(2048ull * 2048 * 2);
  float*  cqkv   = (float*)alloc(4096ull * 2112 * 4);    // fused q_lora | kv_lora | k_pe
  ushort* cqn    = (ushort*)alloc(4096ull * 1536 * 2);
  ushort* ckvn   = (ushort*)alloc(4096ull * 512 * 2);
  ushort* kbuf   = (ushort*)alloc(2ull * 16 * 2048 * 192 * 2);
  ushort* qbuf   = (ushort*)cqkv;   // reuse: cqkv dead after both norms
  ushort* aout   = xb;              // reuse: x dead after fused GEMM1
  ushort* vT     = wqkv_t;          // reuse: wqkv_t+wqb_t dead after GEMM2

  dim3 tb(32, 8);
  k_f32_to_bf16<<<2048, 256, 0, stream>>>(x, xb, 4096 * 2048 / 4);
  k_transpose_f32_bf16<<<dim3(48, 64), tb, 0, stream>>>(wq_a, wqkv_t, 2048, 1536);
  k_transpose_f32_bf16<<<dim3(18, 64), tb, 0, stream>>>(wkv_a, wqkv_t + 1536ull * 2048, 2048, 576);
  k_transpose_f32_bf16<<<dim3(96, 48), tb, 0, stream>>>(wq_b, wqb_t, 1536, 3072);
  k_transpose_f32_bf16<<<dim3(128, 16), tb, 0, stream>>>(wkv_b, wkvb_t, 512, 4096);
  k_transpose_f32_bf16<<<dim3(64, 64), tb, 0, stream>>>(wo, wo_t, 2048, 2048);

  // fused GEMM1: cqkv = xb @ [wq_a | wkv_a]  (M=4096, K=2048, Nreal=2112)
  k_gemm<float><<<dim3(17, 32), 256, 0, stream>>>(xb, wqkv_t, cqkv, 2048, 2112);

  k_rmsnorm_bf16<<<4096, 256, 0, stream>>>(cqkv, qnw, cqn, 1536, 2112);
  k_kvnorm_rope<<<4096, 256, 0, stream>>>(cqkv, kvnw, fcos, fsin, ckvn, kbuf);

  // q = cqn @ wq_b (K=1536, N=3072), bf16 out with FUSED RoPE epilogue
  k_gemm_qrope<<<dim3(24, 32), 256, 0, stream>>>(cqn, wqb_t, qbuf, 1536, fcos, fsin);

  // kv = ckvn @ wkv_b (K=512, N=4096) -> kbuf + vT (scatter epilogue)
  k_gemm_kv<<<dim3(32, 32), 256, 0, stream>>>(ckvn, wkvb_t, kbuf, vT, 512);

  k_attn10<<<dim3(512), 256, 0, stream>>>(qbuf, kbuf, vT, aout);

  // out = aout @ wo (K=2048, N=2048), fp32 out
  k_gemm<float><<<dim3(16, 32), 256, 0, stream>>>(aout, wo_t, out, 2048, 2048);
}

// Round 18
// 350.255 us; speedup vs baseline: 1.1168x; 1.0114x over previous
//
#include <hip/hip_runtime.h>
#include <cstdint>
#include <cstddef>

// ---------------- common types / helpers ----------------
typedef __attribute__((ext_vector_type(8))) short bf16x8;
typedef __attribute__((ext_vector_type(4))) float f32x4;
typedef __attribute__((ext_vector_type(16))) float f32x16;

#define S_LEN 2048
#define SCALE2 0.10411754f   // 192^-0.5 * log2(e)

__device__ __forceinline__ ushort f2bf(float f) {
  uint32_t u = __float_as_uint(f);
  u = (u + 0x7FFFu + ((u >> 16) & 1u)) >> 16;
  return (ushort)u;
}
__device__ __forceinline__ float bf2f(ushort u) {
  return __uint_as_float(((uint32_t)u) << 16);
}

typedef __attribute__((address_space(1))) void GV;
typedef __attribute__((address_space(3))) void LV;
__device__ __forceinline__ void gload16(const void* g, void* l) {
  __builtin_amdgcn_global_load_lds((GV*)g, (LV*)l, 16, 0, 0);
}

__device__ __forceinline__ void store_out(float* p, float v) { *p = v; }
__device__ __forceinline__ void store_out(ushort* p, float v) { *p = f2bf(v); }

// ---------------- fp32 -> bf16 convert ----------------
__global__ void k_f32_to_bf16(const float* __restrict__ in, ushort* __restrict__ out, int n4) {
  int i = blockIdx.x * blockDim.x + threadIdx.x;
  int stride = gridDim.x * blockDim.x;
  for (; i < n4; i += stride) {
    float4 v = reinterpret_cast<const float4*>(in)[i];
    ushort4 o;
    o.x = f2bf(v.x); o.y = f2bf(v.y); o.z = f2bf(v.z); o.w = f2bf(v.w);
    reinterpret_cast<ushort4*>(out)[i] = o;
  }
}

// ---------------- merged weight transposes: 5 segments, one dispatch ----------------
// Each segment transposes fp32 (R,C) -> bf16 (C,R) with the proven 32x33 tile.
// Segment table (grid 1-D, 14976 blocks total):
//   0: wq_a  2048x1536  gx=48  3072 blocks
//   1: wkv_a 2048x576   gx=18  1152
//   2: wq_b  1536x3072  gx=96  4608
//   3: wkv_b 512x4096   gx=128 2048
//   4: wo    2048x2048  gx=64  4096
__global__ void k_transpose_all(const float* __restrict__ s0, const float* __restrict__ s1,
                                const float* __restrict__ s2, const float* __restrict__ s3,
                                const float* __restrict__ s4,
                                ushort* __restrict__ d0, ushort* __restrict__ d1,
                                ushort* __restrict__ d2, ushort* __restrict__ d3,
                                ushort* __restrict__ d4) {
  __shared__ float tile[32][33];
  int id = blockIdx.x;
  const float* in; ushort* out; int R, C, gx, lid;
  if (id < 3072)        { in = s0; out = d0; R = 2048; C = 1536; gx = 48;  lid = id; }
  else if (id < 4224)   { in = s1; out = d1; R = 2048; C = 576;  gx = 18;  lid = id - 3072; }
  else if (id < 8832)   { in = s2; out = d2; R = 1536; C = 3072; gx = 96;  lid = id - 4224; }
  else if (id < 10880)  { in = s3; out = d3; R = 512;  C = 4096; gx = 128; lid = id - 8832; }
  else                  { in = s4; out = d4; R = 2048; C = 2048; gx = 64;  lid = id - 10880; }
  int c0 = (lid % gx) * 32, r0 = (lid / gx) * 32;
  int tx = threadIdx.x, ty = threadIdx.y;
#pragma unroll
  for (int i = 0; i < 32; i += 8) {
    int r = r0 + ty + i, c = c0 + tx;
    if (r < R && c < C) tile[ty + i][tx] = in[(size_t)r * C + c];
  }
  __syncthreads();
#pragma unroll
  for (int i = 0; i < 32; i += 8) {
    int c = c0 + ty + i, r = r0 + tx;
    if (r < R && c < C) out[(size_t)c * R + r] = f2bf(tile[tx][ty + i]);
  }
}

// ---------------- 128x128 BK=64 bf16 GEMM (R15-proven single-buffer form) ----------------
template <typename OUT>
__global__ __launch_bounds__(256) void k_gemm(const ushort* __restrict__ A,
                                              const ushort* __restrict__ Bt,
                                              OUT* __restrict__ C, int K, int Nreal) {
  __shared__ ushort As[128 * 72];   // 18432 B
  __shared__ ushort Bs[128 * 72];   // 18432 B
  const int t = threadIdx.x, lane = t & 63, w = t >> 6;
  const int nwg = gridDim.x * gridDim.y;
  const int wg = blockIdx.y * gridDim.x + blockIdx.x;
  const int swz = (wg & 7) * (nwg >> 3) + (wg >> 3);
  const int m0 = (swz / gridDim.x) * 128, n0 = (swz % gridDim.x) * 128;
  const int wm = (w >> 1) * 64, wn = (w & 1) * 64;
  const int g = lane >> 4, q = lane & 15;
  f32x4 acc[4][4] = {};
  for (int kt = 0; kt < K; kt += 64) {
#pragma unroll
    for (int it = 0; it < 5; ++it) {
      int ii = it * 4 + w;
      if (ii < 18) {
        unsigned s = ii * 64 + lane;         // 0..1151
        int r = s / 9, e = s - r * 9;        // r<128, e<9
        int cg = e ^ ((r >> 3) & 7);
        if (cg > 7) cg = 0;                  // pad slot -> dummy load
        gload16(A + (size_t)(m0 + r) * K + kt + cg * 8, (char*)As + ii * 1024);
        gload16(Bt + (size_t)(n0 + r) * K + kt + cg * 8, (char*)Bs + ii * 1024);
      }
    }
    asm volatile("s_waitcnt vmcnt(0)" ::: "memory");
    __syncthreads();
#pragma unroll
    for (int kh = 0; kh < 2; ++kh) {
      bf16x8 af[4], bfr[4];
#pragma unroll
      for (int mi = 0; mi < 4; mi++) {
        int row = wm + 16 * mi + q;
        int rx = (row >> 3) & 7;
        af[mi] = *(const bf16x8*)(As + row * 72 + (((kh * 4 + g) ^ rx) << 3));
      }
#pragma unroll
      for (int ni = 0; ni < 4; ni++) {
        int row = wn + 16 * ni + q;
        int rx = (row >> 3) & 7;
        bfr[ni] = *(const bf16x8*)(Bs + row * 72 + (((kh * 4 + g) ^ rx) << 3));
      }
#pragma unroll
      for (int mi = 0; mi < 4; mi++)
#pragma unroll
        for (int ni = 0; ni < 4; ni++)
          acc[mi][ni] = __builtin_amdgcn_mfma_f32_16x16x32_bf16(af[mi], bfr[ni], acc[mi][ni], 0, 0, 0);
    }
    __syncthreads();
  }
#pragma unroll
  for (int mi = 0; mi < 4; mi++)
#pragma unroll
    for (int ni = 0; ni < 4; ni++) {
      int col = n0 + wn + 16 * ni + q;
      if (col < Nreal) {
        int row = m0 + wm + 16 * mi + 4 * g;
#pragma unroll
        for (int r = 0; r < 4; r++)
          store_out(&C[(size_t)(row + r) * Nreal + col], acc[mi][ni][r]);
      }
    }
}

// ---------------- GEMM2 variant: q projection with FUSED RoPE epilogue (R17-proven) ----------------
__global__ __launch_bounds__(256) void k_gemm_qrope(const ushort* __restrict__ A,
                                                    const ushort* __restrict__ Bt,
                                                    ushort* __restrict__ C, int K,
                                                    const float* __restrict__ cosT,
                                                    const float* __restrict__ sinT) {
  __shared__ ushort As[128 * 72];
  __shared__ ushort Bs[128 * 72];
  const int t = threadIdx.x, lane = t & 63, w = t >> 6;
  const int nwg = gridDim.x * gridDim.y;
  const int wg = blockIdx.y * gridDim.x + blockIdx.x;
  const int swz = (wg & 7) * (nwg >> 3) + (wg >> 3);
  const int m0 = (swz / gridDim.x) * 128, n0 = (swz % gridDim.x) * 128;
  const int wm = (w >> 1) * 64, wn = (w & 1) * 64;
  const int g = lane >> 4, q = lane & 15;
  f32x4 acc[4][4] = {};
  for (int kt = 0; kt < K; kt += 64) {
#pragma unroll
    for (int it = 0; it < 5; ++it) {
      int ii = it * 4 + w;
      if (ii < 18) {
        unsigned s = ii * 64 + lane;
        int r = s / 9, e = s - r * 9;
        int cg = e ^ ((r >> 3) & 7);
        if (cg > 7) cg = 0;
        gload16(A + (size_t)(m0 + r) * K + kt + cg * 8, (char*)As + ii * 1024);
        gload16(Bt + (size_t)(n0 + r) * K + kt + cg * 8, (char*)Bs + ii * 1024);
      }
    }
    asm volatile("s_waitcnt vmcnt(0)" ::: "memory");
    __syncthreads();
#pragma unroll
    for (int kh = 0; kh < 2; ++kh) {
      bf16x8 af[4], bfr[4];
#pragma unroll
      for (int mi = 0; mi < 4; mi++) {
        int row = wm + 16 * mi + q;
        int rx = (row >> 3) & 7;
        af[mi] = *(const bf16x8*)(As + row * 72 + (((kh * 4 + g) ^ rx) << 3));
      }
#pragma unroll
      for (int ni = 0; ni < 4; ni++) {
        int row = wn + 16 * ni + q;
        int rx = (row >> 3) & 7;
        bfr[ni] = *(const bf16x8*)(Bs + row * 72 + (((kh * 4 + g) ^ rx) << 3));
      }
#pragma unroll
      for (int mi = 0; mi < 4; mi++)
#pragma unroll
        for (int ni = 0; ni < 4; ni++)
          acc[mi][ni] = __builtin_amdgcn_mfma_f32_16x16x32_bf16(af[mi], bfr[ni], acc[mi][ni], 0, 0, 0);
    }
    __syncthreads();
  }
#pragma unroll
  for (int mi = 0; mi < 4; mi++)
#pragma unroll
    for (int ni = 0; ni < 4; ni++) {
      int col = n0 + wn + 16 * ni + q;       // < 3072 always (grid exact)
      int hoff = col % 192;
      int row = m0 + wm + 16 * mi + 4 * g;
      if (hoff < 128) {                      // wave-uniform branch
#pragma unroll
        for (int r = 0; r < 4; r++)
          C[(size_t)(row + r) * 3072 + col] = f2bf(acc[mi][ni][r]);
      } else {
        int i = (hoff - 128) >> 1;           // pair index; same for lanes q,q^1
#pragma unroll
        for (int r = 0; r < 4; r++) {
          int s2 = (row + r) & 2047;
          float c = cosT[s2 * 32 + i], sn = sinT[s2 * 32 + i];
          float v = acc[mi][ni][r];
          float p = __shfl_xor(v, 1);        // partner column's value
          float res = (q & 1) ? (p * sn + v * c) : (v * c - p * sn);
          C[(size_t)(row + r) * 3072 + col] = f2bf(res);
        }
      }
    }
}

// ---------------- kv GEMM (R15-proven single-buffer form): k_nope -> kbuf, V -> vT ----------------
__global__ __launch_bounds__(256) void k_gemm_kv(const ushort* __restrict__ A,
                                                 const ushort* __restrict__ Bt,
                                                 ushort* __restrict__ kbuf,
                                                 ushort* __restrict__ vT, int K) {
  __shared__ ushort As[128 * 72];
  __shared__ ushort Bs[128 * 72];
  const int t = threadIdx.x, lane = t & 63, w = t >> 6;
  const int nwg = gridDim.x * gridDim.y;
  const int wg = blockIdx.y * gridDim.x + blockIdx.x;
  const int swz = (wg & 7) * (nwg >> 3) + (wg >> 3);
  const int m0 = (swz / gridDim.x) * 128, n0 = (swz % gridDim.x) * 128;
  const int wm = (w >> 1) * 64, wn = (w & 1) * 64;
  const int g = lane >> 4, q = lane & 15;
  f32x4 acc[4][4] = {};
  for (int kt = 0; kt < K; kt += 64) {
#pragma unroll
    for (int it = 0; it < 5; ++it) {
      int ii = it * 4 + w;
      if (ii < 18) {
        unsigned s = ii * 64 + lane;
        int r = s / 9, e = s - r * 9;
        int cg = e ^ ((r >> 3) & 7);
        if (cg > 7) cg = 0;
        gload16(A + (size_t)(m0 + r) * K + kt + cg * 8, (char*)As + ii * 1024);
        gload16(Bt + (size_t)(n0 + r) * K + kt + cg * 8, (char*)Bs + ii * 1024);
      }
    }
    asm volatile("s_waitcnt vmcnt(0)" ::: "memory");
    __syncthreads();
#pragma unroll
    for (int kh = 0; kh < 2; ++kh) {
      bf16x8 af[4], bfr[4];
#pragma unroll
      for (int mi = 0; mi < 4; mi++) {
        int row = wm + 16 * mi + q;
        int rx = (row >> 3) & 7;
        af[mi] = *(const bf16x8*)(As + row * 72 + (((kh * 4 + g) ^ rx) << 3));
      }
#pragma unroll
      for (int ni = 0; ni < 4; ni++) {
        int row = wn + 16 * ni + q;
        int rx = (row >> 3) & 7;
        bfr[ni] = *(const bf16x8*)(Bs + row * 72 + (((kh * 4 + g) ^ rx) << 3));
      }
#pragma unroll
      for (int mi = 0; mi < 4; mi++)
#pragma unroll
        for (int ni = 0; ni < 4; ni++)
          acc[mi][ni] = __builtin_amdgcn_mfma_f32_16x16x32_bf16(af[mi], bfr[ni], acc[mi][ni], 0, 0, 0);
    }
    __syncthreads();
  }
#pragma unroll
  for (int mi = 0; mi < 4; mi++)
#pragma unroll
    for (int ni = 0; ni < 4; ni++) {
      int col = n0 + wn + 16 * ni + q;     // 0..4095
      int hh = col >> 8, jj = col & 255;
      int row0 = m0 + wm + 16 * mi + 4 * g;
#pragma unroll
      for (int r = 0; r < 4; r++) {
        int tok = row0 + r;
        int bb = tok >> 11, ss = tok & 2047;
        ushort v = f2bf(acc[mi][ni][r]);
        if (jj < 128)
          kbuf[((size_t)(bb * 16 + hh) * 2048 + ss) * 192 + jj] = v;
        else
          vT[((size_t)(bb * 16 + hh) * 128 + (jj - 128)) * 2048 + ss] = v;
      }
    }
}

// ---------------- RMSNorm (bf16 in strided rows, bf16 out) ----------------
__global__ void k_rmsnorm_bf16(const ushort* __restrict__ in, const float* __restrict__ w,
                               ushort* __restrict__ out, int D, int instride) {
  int row = blockIdx.x;
  const ushort* x = in + (size_t)row * instride;
  ushort* o = out + (size_t)row * D;
  float ss = 0.f;
  for (int i = threadIdx.x; i < D; i += 256) { float v = bf2f(x[i]); ss += v * v; }
#pragma unroll
  for (int m = 1; m < 64; m <<= 1) ss += __shfl_xor(ss, m);
  __shared__ float red[4];
  if ((threadIdx.x & 63) == 0) red[threadIdx.x >> 6] = ss;
  __syncthreads();
  float tot = red[0] + red[1] + red[2] + red[3];
  float sc = rsqrtf(tot / (float)D + 1e-6f);
  for (int i = threadIdx.x; i < D; i += 256) o[i] = f2bf(bf2f(x[i]) * sc * w[i]);
}

// ---------------- kv RMSNorm (512, bf16 in) + k_pe rope broadcast into kbuf ----------------
__global__ void k_kvnorm_rope(const ushort* __restrict__ cqkv, const float* __restrict__ w,
                              const float* __restrict__ cosT, const float* __restrict__ sinT,
                              ushort* __restrict__ ckvn, ushort* __restrict__ kbuf) {
  int tok = blockIdx.x, b = tok >> 11, s = tok & 2047;
  const ushort* x = cqkv + (size_t)tok * 2112 + 1536;
  float ss = 0.f;
  for (int i = threadIdx.x; i < 512; i += 256) { float v = bf2f(x[i]); ss += v * v; }
#pragma unroll
  for (int m = 1; m < 64; m <<= 1) ss += __shfl_xor(ss, m);
  __shared__ float red[4];
  if ((threadIdx.x & 63) == 0) red[threadIdx.x >> 6] = ss;
  __syncthreads();
  float tot = red[0] + red[1] + red[2] + red[3];
  float sc = rsqrtf(tot / 512.f + 1e-6f);
  for (int i = threadIdx.x; i < 512; i += 256) ckvn[(size_t)tok * 512 + i] = f2bf(bf2f(x[i]) * sc * w[i]);
  if (threadIdx.x < 32) {
    int i = threadIdx.x;
    float xr = bf2f(x[512 + 2 * i]), xi = bf2f(x[512 + 2 * i + 1]);
    float c = cosT[s * 32 + i], sn = sinT[s * 32 + i];
    uint32_t lo = f2bf(xr * c - xi * sn);
    uint32_t hi = f2bf(xr * sn + xi * c);
    uint32_t pk = lo | (hi << 16);
#pragma unroll
    for (int h = 0; h < 16; ++h)
      *(uint32_t*)(kbuf + ((size_t)(b * 16 + h) * 2048 + s) * 192 + 128 + 2 * i) = pk;
  }
}

// ---------------- causal flash attention (R14-proven: 112.4 us) ----------------
__global__ __launch_bounds__(256, 2) void k_attn10(const ushort* __restrict__ qb,
                                                   const ushort* __restrict__ kb,
                                                   const ushort* __restrict__ vT,
                                                   ushort* __restrict__ aout) {
  const int id = blockIdx.x;
  const int qt = 15 - (id >> 5);             // heavy-first (R7-proven mapping)
  const int bh = id & 31;
  const int h = bh & 15, b = bh >> 4;

  const int t = threadIdx.x, lane = t & 63, w = t >> 6;
  const int lq = lane & 31, hi = lane >> 5;
  const int kx = (lq >> 3) & 3;

  __shared__ ushort Ks[64 * 200];   // 25600 B
  __shared__ ushort Vs[128 * 72];   // 18432 B

  const ushort* kh = kb + (size_t)(b * 16 + h) * (2048 * 192);
  const ushort* vh = vT + (size_t)(b * 16 + h) * (128 * 2048);

  auto stage = [&](int k0) {
#pragma unroll
    for (int it = 0; it < 7; ++it) {
      int ii = it * 4 + w;
      if (ii < 25) {
        unsigned s = ii * 64 + lane;         // 0..1599
        int r = s / 25, e = s - r * 25;      // r<64, e<25 (e==24 pad)
        int cg = e ^ ((r >> 3) & 3);
        if (cg > 23) cg = 0;
        gload16(kh + (size_t)(k0 + r) * 192 + cg * 8, (char*)Ks + ii * 1024);
      }
    }
#pragma unroll
    for (int it = 0; it < 5; ++it) {
      int ii = it * 4 + w;
      if (ii < 18) {
        unsigned s = ii * 64 + lane;         // 0..1151
        int r = s / 9, e = s - r * 9;        // r<128, e<9 (e==8 pad)
        int cg = e ^ ((r >> 3) & 7);
        if (cg > 7) cg = 0;
        gload16(vh + (size_t)r * 2048 + k0 + cg * 8, (char*)Vs + ii * 1024);
      }
    }
  };

  const int q0 = qt * 128;
  const int q0w = q0 + 32 * w;
  const int qg = q0w + lq;
  const int nkt = qt * 2 + 2;

  bf16x8 qf[12];
  {
    const ushort* qp = qb + ((size_t)(b * 2048 + qg) * 16 + h) * 192 + 8 * hi;
#pragma unroll
    for (int s = 0; s < 12; ++s) qf[s] = *(const bf16x8*)(qp + 16 * s);
  }

  f32x16 oacc[4];
#pragma unroll
  for (int db = 0; db < 4; ++db)
#pragma unroll
    for (int r = 0; r < 16; ++r) oacc[db][r] = 0.f;
  float m = -1e30f, l = 0.f;

  for (int kt = 0; kt < nkt; ++kt) {
    const int k0 = kt * 64;
    stage(k0);
    asm volatile("s_waitcnt vmcnt(0)" ::: "memory");
    __syncthreads();
    if (k0 <= q0w + 31) {
      f32x16 sA, sB;
#pragma unroll
      for (int r = 0; r < 16; ++r) { sA[r] = 0.f; sB[r] = 0.f; }
      __builtin_amdgcn_s_setprio(1);
#pragma unroll
      for (int s = 0; s < 12; ++s) {
        int ch = ((2 * s + hi) ^ kx) << 3;
        bf16x8 kfA = *(const bf16x8*)(Ks + lq * 200 + ch);
        bf16x8 kfB = *(const bf16x8*)(Ks + (lq + 32) * 200 + ch);
        sA = __builtin_amdgcn_mfma_f32_32x32x16_bf16(kfA, qf[s], sA, 0, 0, 0);
        sB = __builtin_amdgcn_mfma_f32_32x32x16_bf16(kfB, qf[s], sB, 0, 0, 0);
      }
      __builtin_amdgcn_s_setprio(0);
      float svA[16], svB[16];
#pragma unroll
      for (int r = 0; r < 16; ++r) { svA[r] = sA[r]; svB[r] = sB[r]; }
      if (k0 + 63 > q0w) {
#pragma unroll
        for (int r = 0; r < 16; ++r) {
          int kk = (r & 3) + 8 * (r >> 2) + 4 * hi;
          if (k0 + kk > qg) svA[r] = -1e30f;
          if (k0 + 32 + kk > qg) svB[r] = -1e30f;
        }
      }
      float pmax = fmaxf(svA[0], svB[0]);
#pragma unroll
      for (int r = 1; r < 16; ++r) pmax = fmaxf(pmax, fmaxf(svA[r], svB[r]));
      pmax = fmaxf(pmax, __shfl_xor(pmax, 32));
      float smax = pmax * SCALE2;
      if (!__all(smax - m <= 8.0f)) {
        float mnew = fmaxf(m, smax);
        float a = exp2f(m - mnew);
        l *= a;
#pragma unroll
        for (int db = 0; db < 4; ++db)
#pragma unroll
          for (int r = 0; r < 16; ++r) oacc[db][r] *= a;
        m = mnew;
      }
      float eA[16], eB[16]; float sum = 0.f;
#pragma unroll
      for (int r = 0; r < 16; ++r) {
        eA[r] = exp2f(svA[r] * SCALE2 - m);
        eB[r] = exp2f(svB[r] * SCALE2 - m);
        sum += eA[r] + eB[r];
      }
      sum += __shfl_xor(sum, 32);
      l += sum;
      uint32_t pkA[8], pkB[8];
#pragma unroll
      for (int i = 0; i < 8; ++i) {
        pkA[i] = (uint32_t)f2bf(eA[2 * i]) | ((uint32_t)f2bf(eA[2 * i + 1]) << 16);
        pkB[i] = (uint32_t)f2bf(eB[2 * i]) | ((uint32_t)f2bf(eB[2 * i + 1]) << 16);
      }
      uint32_t swA[8], swB[8];
#pragma unroll
      for (int i = 0; i < 8; ++i) {
        swA[i] = (uint32_t)__shfl_xor((int)pkA[i], 32);
        swB[i] = (uint32_t)__shfl_xor((int)pkB[i], 32);
      }
      union { uint32_t u[4]; bf16x8 v; } pA0, pA1, pB0, pB1;
      pA0.u[0] = hi ? swA[2] : pkA[0];
      pA0.u[1] = hi ? swA[3] : pkA[1];
      pA0.u[2] = hi ? pkA[2] : swA[0];
      pA0.u[3] = hi ? pkA[3] : swA[1];
      pA1.u[0] = hi ? swA[6] : pkA[4];
      pA1.u[1] = hi ? swA[7] : pkA[5];
      pA1.u[2] = hi ? pkA[6] : swA[4];
      pA1.u[3] = hi ? pkA[7] : swA[5];
      pB0.u[0] = hi ? swB[2] : pkB[0];
      pB0.u[1] = hi ? swB[3] : pkB[1];
      pB0.u[2] = hi ? pkB[2] : swB[0];
      pB0.u[3] = hi ? pkB[3] : swB[1];
      pB1.u[0] = hi ? swB[6] : pkB[4];
      pB1.u[1] = hi ? swB[7] : pkB[5];
      pB1.u[2] = hi ? pkB[6] : swB[4];
      pB1.u[3] = hi ? pkB[7] : swB[5];
      __builtin_amdgcn_s_setprio(1);
#pragma unroll
      for (int db = 0; db < 4; ++db) {
        const int d = 32 * db + lq;
        const int vx = (d >> 3) & 7;
        const ushort* vr = Vs + d * 72;
        bf16x8 vf0 = *(const bf16x8*)(vr + (((0 + hi) ^ vx) << 3));
        bf16x8 vf1 = *(const bf16x8*)(vr + (((2 + hi) ^ vx) << 3));
        bf16x8 vf2 = *(const bf16x8*)(vr + (((4 + hi) ^ vx) << 3));
        bf16x8 vf3 = *(const bf16x8*)(vr + (((6 + hi) ^ vx) << 3));
        oacc[db] = __builtin_amdgcn_mfma_f32_32x32x16_bf16(vf0, pA0.v, oacc[db], 0, 0, 0);
        oacc[db] = __builtin_amdgcn_mfma_f32_32x32x16_bf16(vf1, pA1.v, oacc[db], 0, 0, 0);
        oacc[db] = __builtin_amdgcn_mfma_f32_32x32x16_bf16(vf2, pB0.v, oacc[db], 0, 0, 0);
        oacc[db] = __builtin_amdgcn_mfma_f32_32x32x16_bf16(vf3, pB1.v, oacc[db], 0, 0, 0);
      }
      __builtin_amdgcn_s_setprio(0);
    }
    asm volatile("s_waitcnt lgkmcnt(0)" ::: "memory");
    __syncthreads();
  }

  float inv = 1.f / l;
  ushort* op = aout + ((size_t)(b * 2048 + qg)) * 2048 + h * 128 + 4 * hi;
#pragma unroll
  for (int db = 0; db < 4; ++db)
#pragma unroll
    for (int i = 0; i < 8; ++i) {
      uint32_t u = (uint32_t)f2bf(oacc[db][2 * i] * inv) |
                   ((uint32_t)f2bf(oacc[db][2 * i + 1] * inv) << 16);
      int dbase = 32 * db + (i & 1) * 2 + (i >> 1) * 8;
      *(uint32_t*)(op + dbase) = u;
    }
}

// ---------------- launcher ----------------
extern "C" void kernel_launch(void* const* d_in, const int* in_sizes, int n_in,
                              void* d_out, int out_size, void* d_ws, size_t ws_size,
                              hipStream_t stream) {
  const float* x = (const float*)d_in[0];
  const float* fcos = (const float*)d_in[1];
  const float* fsin = (const float*)d_in[2];
  const float* wq_a = (const float*)d_in[3];
  const float* qnw = (const float*)d_in[4];
  const float* wq_b = (const float*)d_in[5];
  const float* wkv_a = (const float*)d_in[6];
  const float* kvnw = (const float*)d_in[7];
  const float* wkv_b = (const float*)d_in[8];
  const float* wo = (const float*)d_in[9];
  float* out = (float*)d_out;

  char* ws = (char*)d_ws;
  size_t off = 0;
  auto alloc = [&](size_t bytes) -> char* {
    char* p = ws + off;
    off += (bytes + 255) & ~(size_t)255;
    return p;
  };
  ushort* xb     = (ushort*)alloc(4096ull * 2048 * 2);
  ushort* wqkv_t = (ushort*)alloc(2176ull * 2048 * 2);   // rows 0-1535 wq_a^T, 1536-2111 wkv_a^T, rest pad
  ushort* wqb_t  = (ushort*)alloc(3072ull * 1536 * 2);
  ushort* wkvb_t = (ushort*)alloc(4096ull * 512 * 2);
  ushort* wo_t   = (ushort*)alloc(2048ull * 2048 * 2);
  ushort* cqkv   = (ushort*)alloc(4096ull * 2112 * 2);   // fused q_lora | kv_lora | k_pe (bf16)
  ushort* cqn    = (ushort*)alloc(4096ull * 1536 * 2);
  ushort* ckvn   = (ushort*)alloc(4096ull * 512 * 2);
  ushort* kbuf   = (ushort*)alloc(2ull * 16 * 2048 * 192 * 2);
  ushort* qbuf   = (ushort*)alloc(4096ull * 3072 * 2);   // q projection output
  ushort* aout   = xb;              // reuse: x dead after fused GEMM1
  ushort* vT     = wqkv_t;          // reuse: wqkv_t+wqb_t dead after GEMM2

  k_f32_to_bf16<<<2048, 256, 0, stream>>>(x, xb, 4096 * 2048 / 4);
  // merged transposes: wq_a|wkv_a -> wqkv_t (fused), wq_b, wkv_b, wo
  k_transpose_all<<<14976, dim3(32, 8), 0, stream>>>(
      wq_a, wkv_a, wq_b, wkv_b, wo,
      wqkv_t, wqkv_t + 1536ull * 2048, wqb_t, wkvb_t, wo_t);

  // fused GEMM1: cqkv = xb @ [wq_a | wkv_a]  (M=4096, K=2048, Nreal=2112), bf16 out
  k_gemm<ushort><<<dim3(17, 32), 256, 0, stream>>>(xb, wqkv_t, cqkv, 2048, 2112);

  k_rmsnorm_bf16<<<4096, 256, 0, stream>>>(cqkv, qnw, cqn, 1536, 2112);
  k_kvnorm_rope<<<4096, 256, 0, stream>>>(cqkv, kvnw, fcos, fsin, ckvn, kbuf);

  // q = cqn @ wq_b (K=1536, N=3072), bf16 out with FUSED RoPE epilogue
  k_gemm_qrope<<<dim3(24, 32), 256, 0, stream>>>(cqn, wqb_t, qbuf, 1536, fcos, fsin);

  // kv = ckvn @ wkv_b (K=512, N=4096) -> kbuf + vT (scatter epilogue)
  k_gemm_kv<<<dim3(32, 32), 256, 0, stream>>>(ckvn, wkvb_t, kbuf, vT, 512);

  k_attn10<<<dim3(512), 256, 0, stream>>>(qbuf, kbuf, vT, aout);

  // out = aout @ wo (K=2048, N=2048), fp32 out
  k_gemm<float><<<dim3(16, 32), 256, 0, stream>>>(aout, wo_t, out, 2048, 2048);
}

// Round 19
// 342.839 us; speedup vs baseline: 1.1409x; 1.0216x over previous
//
#include <hip/hip_runtime.h>
#include <cstdint>
#include <cstddef>

// ---------------- common types / helpers ----------------
typedef __attribute__((ext_vector_type(8))) short bf16x8;
typedef __attribute__((ext_vector_type(4))) float f32x4;
typedef __attribute__((ext_vector_type(16))) float f32x16;

#define S_LEN 2048
#define SCALE2 0.10411754f   // 192^-0.5 * log2(e)

__device__ __forceinline__ ushort f2bf(float f) {
  uint32_t u = __float_as_uint(f);
  u = (u + 0x7FFFu + ((u >> 16) & 1u)) >> 16;
  return (ushort)u;
}
__device__ __forceinline__ float bf2f(ushort u) {
  return __uint_as_float(((uint32_t)u) << 16);
}

typedef __attribute__((address_space(1))) void GV;
typedef __attribute__((address_space(3))) void LV;
__device__ __forceinline__ void gload16(const void* g, void* l) {
  __builtin_amdgcn_global_load_lds((GV*)g, (LV*)l, 16, 0, 0);
}

__device__ __forceinline__ void store_out(float* p, float v) { *p = v; }
__device__ __forceinline__ void store_out(ushort* p, float v) { *p = f2bf(v); }

// ---------------- fp32 -> bf16 convert ----------------
__global__ void k_f32_to_bf16(const float* __restrict__ in, ushort* __restrict__ out, int n4) {
  int i = blockIdx.x * blockDim.x + threadIdx.x;
  int stride = gridDim.x * blockDim.x;
  for (; i < n4; i += stride) {
    float4 v = reinterpret_cast<const float4*>(in)[i];
    ushort4 o;
    o.x = f2bf(v.x); o.y = f2bf(v.y); o.z = f2bf(v.z); o.w = f2bf(v.w);
    reinterpret_cast<ushort4*>(out)[i] = o;
  }
}

// ---------------- merged weight transposes: 5 segments, one dispatch ----------------
__global__ void k_transpose_all(const float* __restrict__ s0, const float* __restrict__ s1,
                                const float* __restrict__ s2, const float* __restrict__ s3,
                                const float* __restrict__ s4,
                                ushort* __restrict__ d0, ushort* __restrict__ d1,
                                ushort* __restrict__ d2, ushort* __restrict__ d3,
                                ushort* __restrict__ d4) {
  __shared__ float tile[32][33];
  int id = blockIdx.x;
  const float* in; ushort* out; int R, C, gx, lid;
  if (id < 3072)        { in = s0; out = d0; R = 2048; C = 1536; gx = 48;  lid = id; }
  else if (id < 4224)   { in = s1; out = d1; R = 2048; C = 576;  gx = 18;  lid = id - 3072; }
  else if (id < 8832)   { in = s2; out = d2; R = 1536; C = 3072; gx = 96;  lid = id - 4224; }
  else if (id < 10880)  { in = s3; out = d3; R = 512;  C = 4096; gx = 128; lid = id - 8832; }
  else                  { in = s4; out = d4; R = 2048; C = 2048; gx = 64;  lid = id - 10880; }
  int c0 = (lid % gx) * 32, r0 = (lid / gx) * 32;
  int tx = threadIdx.x, ty = threadIdx.y;
#pragma unroll
  for (int i = 0; i < 32; i += 8) {
    int r = r0 + ty + i, c = c0 + tx;
    if (r < R && c < C) tile[ty + i][tx] = in[(size_t)r * C + c];
  }
  __syncthreads();
#pragma unroll
  for (int i = 0; i < 32; i += 8) {
    int c = c0 + ty + i, r = r0 + tx;
    if (r < R && c < C) out[(size_t)c * R + r] = f2bf(tile[tx][ty + i]);
  }
}

// ---------------- 128x128 BK=64 bf16 GEMM (R15-proven single-buffer form) ----------------
template <typename OUT>
__global__ __launch_bounds__(256) void k_gemm(const ushort* __restrict__ A,
                                              const ushort* __restrict__ Bt,
                                              OUT* __restrict__ C, int K, int Nreal) {
  __shared__ ushort As[128 * 72];   // 18432 B
  __shared__ ushort Bs[128 * 72];   // 18432 B
  const int t = threadIdx.x, lane = t & 63, w = t >> 6;
  const int nwg = gridDim.x * gridDim.y;
  const int wg = blockIdx.y * gridDim.x + blockIdx.x;
  const int swz = (wg & 7) * (nwg >> 3) + (wg >> 3);
  const int m0 = (swz / gridDim.x) * 128, n0 = (swz % gridDim.x) * 128;
  const int wm = (w >> 1) * 64, wn = (w & 1) * 64;
  const int g = lane >> 4, q = lane & 15;
  f32x4 acc[4][4] = {};
  for (int kt = 0; kt < K; kt += 64) {
#pragma unroll
    for (int it = 0; it < 5; ++it) {
      int ii = it * 4 + w;
      if (ii < 18) {
        unsigned s = ii * 64 + lane;         // 0..1151
        int r = s / 9, e = s - r * 9;        // r<128, e<9
        int cg = e ^ ((r >> 3) & 7);
        if (cg > 7) cg = 0;                  // pad slot -> dummy load
        gload16(A + (size_t)(m0 + r) * K + kt + cg * 8, (char*)As + ii * 1024);
        gload16(Bt + (size_t)(n0 + r) * K + kt + cg * 8, (char*)Bs + ii * 1024);
      }
    }
    asm volatile("s_waitcnt vmcnt(0)" ::: "memory");
    __syncthreads();
#pragma unroll
    for (int kh = 0; kh < 2; ++kh) {
      bf16x8 af[4], bfr[4];
#pragma unroll
      for (int mi = 0; mi < 4; mi++) {
        int row = wm + 16 * mi + q;
        int rx = (row >> 3) & 7;
        af[mi] = *(const bf16x8*)(As + row * 72 + (((kh * 4 + g) ^ rx) << 3));
      }
#pragma unroll
      for (int ni = 0; ni < 4; ni++) {
        int row = wn + 16 * ni + q;
        int rx = (row >> 3) & 7;
        bfr[ni] = *(const bf16x8*)(Bs + row * 72 + (((kh * 4 + g) ^ rx) << 3));
      }
#pragma unroll
      for (int mi = 0; mi < 4; mi++)
#pragma unroll
        for (int ni = 0; ni < 4; ni++)
          acc[mi][ni] = __builtin_amdgcn_mfma_f32_16x16x32_bf16(af[mi], bfr[ni], acc[mi][ni], 0, 0, 0);
    }
    __syncthreads();
  }
#pragma unroll
  for (int mi = 0; mi < 4; mi++)
#pragma unroll
    for (int ni = 0; ni < 4; ni++) {
      int col = n0 + wn + 16 * ni + q;
      if (col < Nreal) {
        int row = m0 + wm + 16 * mi + 4 * g;
#pragma unroll
        for (int r = 0; r < 4; r++)
          store_out(&C[(size_t)(row + r) * Nreal + col], acc[mi][ni][r]);
      }
    }
}

// ---------------- GEMM2 variant: q projection with FUSED RoPE epilogue (R17-proven) ----------------
__global__ __launch_bounds__(256) void k_gemm_qrope(const ushort* __restrict__ A,
                                                    const ushort* __restrict__ Bt,
                                                    ushort* __restrict__ C, int K,
                                                    const float* __restrict__ cosT,
                                                    const float* __restrict__ sinT) {
  __shared__ ushort As[128 * 72];
  __shared__ ushort Bs[128 * 72];
  const int t = threadIdx.x, lane = t & 63, w = t >> 6;
  const int nwg = gridDim.x * gridDim.y;
  const int wg = blockIdx.y * gridDim.x + blockIdx.x;
  const int swz = (wg & 7) * (nwg >> 3) + (wg >> 3);
  const int m0 = (swz / gridDim.x) * 128, n0 = (swz % gridDim.x) * 128;
  const int wm = (w >> 1) * 64, wn = (w & 1) * 64;
  const int g = lane >> 4, q = lane & 15;
  f32x4 acc[4][4] = {};
  for (int kt = 0; kt < K; kt += 64) {
#pragma unroll
    for (int it = 0; it < 5; ++it) {
      int ii = it * 4 + w;
      if (ii < 18) {
        unsigned s = ii * 64 + lane;
        int r = s / 9, e = s - r * 9;
        int cg = e ^ ((r >> 3) & 7);
        if (cg > 7) cg = 0;
        gload16(A + (size_t)(m0 + r) * K + kt + cg * 8, (char*)As + ii * 1024);
        gload16(Bt + (size_t)(n0 + r) * K + kt + cg * 8, (char*)Bs + ii * 1024);
      }
    }
    asm volatile("s_waitcnt vmcnt(0)" ::: "memory");
    __syncthreads();
#pragma unroll
    for (int kh = 0; kh < 2; ++kh) {
      bf16x8 af[4], bfr[4];
#pragma unroll
      for (int mi = 0; mi < 4; mi++) {
        int row = wm + 16 * mi + q;
        int rx = (row >> 3) & 7;
        af[mi] = *(const bf16x8*)(As + row * 72 + (((kh * 4 + g) ^ rx) << 3));
      }
#pragma unroll
      for (int ni = 0; ni < 4; ni++) {
        int row = wn + 16 * ni + q;
        int rx = (row >> 3) & 7;
        bfr[ni] = *(const bf16x8*)(Bs + row * 72 + (((kh * 4 + g) ^ rx) << 3));
      }
#pragma unroll
      for (int mi = 0; mi < 4; mi++)
#pragma unroll
        for (int ni = 0; ni < 4; ni++)
          acc[mi][ni] = __builtin_amdgcn_mfma_f32_16x16x32_bf16(af[mi], bfr[ni], acc[mi][ni], 0, 0, 0);
    }
    __syncthreads();
  }
#pragma unroll
  for (int mi = 0; mi < 4; mi++)
#pragma unroll
    for (int ni = 0; ni < 4; ni++) {
      int col = n0 + wn + 16 * ni + q;       // < 3072 always (grid exact)
      int hoff = col % 192;
      int row = m0 + wm + 16 * mi + 4 * g;
      if (hoff < 128) {                      // wave-uniform branch
#pragma unroll
        for (int r = 0; r < 4; r++)
          C[(size_t)(row + r) * 3072 + col] = f2bf(acc[mi][ni][r]);
      } else {
        int i = (hoff - 128) >> 1;           // pair index; same for lanes q,q^1
#pragma unroll
        for (int r = 0; r < 4; r++) {
          int s2 = (row + r) & 2047;
          float c = cosT[s2 * 32 + i], sn = sinT[s2 * 32 + i];
          float v = acc[mi][ni][r];
          float p = __shfl_xor(v, 1);        // partner column's value
          float res = (q & 1) ? (p * sn + v * c) : (v * c - p * sn);
          C[(size_t)(row + r) * 3072 + col] = f2bf(res);
        }
      }
    }
}

// ---------------- kv GEMM (R15-proven single-buffer form): k_nope -> kbuf, V -> vT ----------------
__global__ __launch_bounds__(256) void k_gemm_kv(const ushort* __restrict__ A,
                                                 const ushort* __restrict__ Bt,
                                                 ushort* __restrict__ kbuf,
                                                 ushort* __restrict__ vT, int K) {
  __shared__ ushort As[128 * 72];
  __shared__ ushort Bs[128 * 72];
  const int t = threadIdx.x, lane = t & 63, w = t >> 6;
  const int nwg = gridDim.x * gridDim.y;
  const int wg = blockIdx.y * gridDim.x + blockIdx.x;
  const int swz = (wg & 7) * (nwg >> 3) + (wg >> 3);
  const int m0 = (swz / gridDim.x) * 128, n0 = (swz % gridDim.x) * 128;
  const int wm = (w >> 1) * 64, wn = (w & 1) * 64;
  const int g = lane >> 4, q = lane & 15;
  f32x4 acc[4][4] = {};
  for (int kt = 0; kt < K; kt += 64) {
#pragma unroll
    for (int it = 0; it < 5; ++it) {
      int ii = it * 4 + w;
      if (ii < 18) {
        unsigned s = ii * 64 + lane;
        int r = s / 9, e = s - r * 9;
        int cg = e ^ ((r >> 3) & 7);
        if (cg > 7) cg = 0;
        gload16(A + (size_t)(m0 + r) * K + kt + cg * 8, (char*)As + ii * 1024);
        gload16(Bt + (size_t)(n0 + r) * K + kt + cg * 8, (char*)Bs + ii * 1024);
      }
    }
    asm volatile("s_waitcnt vmcnt(0)" ::: "memory");
    __syncthreads();
#pragma unroll
    for (int kh = 0; kh < 2; ++kh) {
      bf16x8 af[4], bfr[4];
#pragma unroll
      for (int mi = 0; mi < 4; mi++) {
        int row = wm + 16 * mi + q;
        int rx = (row >> 3) & 7;
        af[mi] = *(const bf16x8*)(As + row * 72 + (((kh * 4 + g) ^ rx) << 3));
      }
#pragma unroll
      for (int ni = 0; ni < 4; ni++) {
        int row = wn + 16 * ni + q;
        int rx = (row >> 3) & 7;
        bfr[ni] = *(const bf16x8*)(Bs + row * 72 + (((kh * 4 + g) ^ rx) << 3));
      }
#pragma unroll
      for (int mi = 0; mi < 4; mi++)
#pragma unroll
        for (int ni = 0; ni < 4; ni++)
          acc[mi][ni] = __builtin_amdgcn_mfma_f32_16x16x32_bf16(af[mi], bfr[ni], acc[mi][ni], 0, 0, 0);
    }
    __syncthreads();
  }
#pragma unroll
  for (int mi = 0; mi < 4; mi++)
#pragma unroll
    for (int ni = 0; ni < 4; ni++) {
      int col = n0 + wn + 16 * ni + q;     // 0..4095
      int hh = col >> 8, jj = col & 255;
      int row0 = m0 + wm + 16 * mi + 4 * g;
#pragma unroll
      for (int r = 0; r < 4; r++) {
        int tok = row0 + r;
        int bb = tok >> 11, ss = tok & 2047;
        ushort v = f2bf(acc[mi][ni][r]);
        if (jj < 128)
          kbuf[((size_t)(bb * 16 + hh) * 2048 + ss) * 192 + jj] = v;
        else
          vT[((size_t)(bb * 16 + hh) * 128 + (jj - 128)) * 2048 + ss] = v;
      }
    }
}

// ---------------- RMSNorm (bf16 in strided rows, bf16 out) ----------------
__global__ void k_rmsnorm_bf16(const ushort* __restrict__ in, const float* __restrict__ w,
                               ushort* __restrict__ out, int D, int instride) {
  int row = blockIdx.x;
  const ushort* x = in + (size_t)row * instride;
  ushort* o = out + (size_t)row * D;
  float ss = 0.f;
  for (int i = threadIdx.x; i < D; i += 256) { float v = bf2f(x[i]); ss += v * v; }
#pragma unroll
  for (int m = 1; m < 64; m <<= 1) ss += __shfl_xor(ss, m);
  __shared__ float red[4];
  if ((threadIdx.x & 63) == 0) red[threadIdx.x >> 6] = ss;
  __syncthreads();
  float tot = red[0] + red[1] + red[2] + red[3];
  float sc = rsqrtf(tot / (float)D + 1e-6f);
  for (int i = threadIdx.x; i < D; i += 256) o[i] = f2bf(bf2f(x[i]) * sc * w[i]);
}

// ---------------- kv RMSNorm (512, bf16 in) + k_pe rope broadcast into kbuf ----------------
__global__ void k_kvnorm_rope(const ushort* __restrict__ cqkv, const float* __restrict__ w,
                              const float* __restrict__ cosT, const float* __restrict__ sinT,
                              ushort* __restrict__ ckvn, ushort* __restrict__ kbuf) {
  int tok = blockIdx.x, b = tok >> 11, s = tok & 2047;
  const ushort* x = cqkv + (size_t)tok * 2112 + 1536;
  float ss = 0.f;
  for (int i = threadIdx.x; i < 512; i += 256) { float v = bf2f(x[i]); ss += v * v; }
#pragma unroll
  for (int m = 1; m < 64; m <<= 1) ss += __shfl_xor(ss, m);
  __shared__ float red[4];
  if ((threadIdx.x & 63) == 0) red[threadIdx.x >> 6] = ss;
  __syncthreads();
  float tot = red[0] + red[1] + red[2] + red[3];
  float sc = rsqrtf(tot / 512.f + 1e-6f);
  for (int i = threadIdx.x; i < 512; i += 256) ckvn[(size_t)tok * 512 + i] = f2bf(bf2f(x[i]) * sc * w[i]);
  if (threadIdx.x < 32) {
    int i = threadIdx.x;
    float xr = bf2f(x[512 + 2 * i]), xi = bf2f(x[512 + 2 * i + 1]);
    float c = cosT[s * 32 + i], sn = sinT[s * 32 + i];
    uint32_t lo = f2bf(xr * c - xi * sn);
    uint32_t hi = f2bf(xr * sn + xi * c);
    uint32_t pk = lo | (hi << 16);
#pragma unroll
    for (int h = 0; h < 16; ++h)
      *(uint32_t*)(kbuf + ((size_t)(b * 16 + h) * 2048 + s) * 192 + 128 + 2 * i) = pk;
  }
}

// ---------------- causal flash attention (R14 kernel, R19: anti-symmetric qt mapping) ----------------
// R19 SINGLE delta vs R18: qt mapping. Heavy-first made CU pair {c, c+256}
// carry (15-(c>>5)) + (7-(c>>5)) = 8..22 iteration-units (max at c=0).
// Anti-symmetric mapping pairs qt=15-(c>>5) with qt=(c>>5): constant 15.
// (R13 bundled this with chain-split (+8 VGPR) and tree-reduce; net regressed.
// This isolates the mapping on the proven R14/R18 kernel bytes.)
__global__ __launch_bounds__(256, 2) void k_attn10(const ushort* __restrict__ qb,
                                                   const ushort* __restrict__ kb,
                                                   const ushort* __restrict__ vT,
                                                   ushort* __restrict__ aout) {
  const int id = blockIdx.x;
  const int qt = (id < 256) ? (15 - (id >> 5)) : ((id - 256) >> 5);
  const int bh = id & 31;
  const int h = bh & 15, b = bh >> 4;

  const int t = threadIdx.x, lane = t & 63, w = t >> 6;
  const int lq = lane & 31, hi = lane >> 5;
  const int kx = (lq >> 3) & 3;

  __shared__ ushort Ks[64 * 200];   // 25600 B
  __shared__ ushort Vs[128 * 72];   // 18432 B

  const ushort* kh = kb + (size_t)(b * 16 + h) * (2048 * 192);
  const ushort* vh = vT + (size_t)(b * 16 + h) * (128 * 2048);

  auto stage = [&](int k0) {
#pragma unroll
    for (int it = 0; it < 7; ++it) {
      int ii = it * 4 + w;
      if (ii < 25) {
        unsigned s = ii * 64 + lane;         // 0..1599
        int r = s / 25, e = s - r * 25;      // r<64, e<25 (e==24 pad)
        int cg = e ^ ((r >> 3) & 3);
        if (cg > 23) cg = 0;
        gload16(kh + (size_t)(k0 + r) * 192 + cg * 8, (char*)Ks + ii * 1024);
      }
    }
#pragma unroll
    for (int it = 0; it < 5; ++it) {
      int ii = it * 4 + w;
      if (ii < 18) {
        unsigned s = ii * 64 + lane;         // 0..1151
        int r = s / 9, e = s - r * 9;        // r<128, e<9 (e==8 pad)
        int cg = e ^ ((r >> 3) & 7);
        if (cg > 7) cg = 0;
        gload16(vh + (size_t)r * 2048 + k0 + cg * 8, (char*)Vs + ii * 1024);
      }
    }
  };

  const int q0 = qt * 128;
  const int q0w = q0 + 32 * w;
  const int qg = q0w + lq;
  const int nkt = qt * 2 + 2;

  bf16x8 qf[12];
  {
    const ushort* qp = qb + ((size_t)(b * 2048 + qg) * 16 + h) * 192 + 8 * hi;
#pragma unroll
    for (int s = 0; s < 12; ++s) qf[s] = *(const bf16x8*)(qp + 16 * s);
  }

  f32x16 oacc[4];
#pragma unroll
  for (int db = 0; db < 4; ++db)
#pragma unroll
    for (int r = 0; r < 16; ++r) oacc[db][r] = 0.f;
  float m = -1e30f, l = 0.f;

  for (int kt = 0; kt < nkt; ++kt) {
    const int k0 = kt * 64;
    stage(k0);
    asm volatile("s_waitcnt vmcnt(0)" ::: "memory");
    __syncthreads();
    if (k0 <= q0w + 31) {
      f32x16 sA, sB;
#pragma unroll
      for (int r = 0; r < 16; ++r) { sA[r] = 0.f; sB[r] = 0.f; }
      __builtin_amdgcn_s_setprio(1);
#pragma unroll
      for (int s = 0; s < 12; ++s) {
        int ch = ((2 * s + hi) ^ kx) << 3;
        bf16x8 kfA = *(const bf16x8*)(Ks + lq * 200 + ch);
        bf16x8 kfB = *(const bf16x8*)(Ks + (lq + 32) * 200 + ch);
        sA = __builtin_amdgcn_mfma_f32_32x32x16_bf16(kfA, qf[s], sA, 0, 0, 0);
        sB = __builtin_amdgcn_mfma_f32_32x32x16_bf16(kfB, qf[s], sB, 0, 0, 0);
      }
      __builtin_amdgcn_s_setprio(0);
      float svA[16], svB[16];
#pragma unroll
      for (int r = 0; r < 16; ++r) { svA[r] = sA[r]; svB[r] = sB[r]; }
      if (k0 + 63 > q0w) {
#pragma unroll
        for (int r = 0; r < 16; ++r) {
          int kk = (r & 3) + 8 * (r >> 2) + 4 * hi;
          if (k0 + kk > qg) svA[r] = -1e30f;
          if (k0 + 32 + kk > qg) svB[r] = -1e30f;
        }
      }
      float pmax = fmaxf(svA[0], svB[0]);
#pragma unroll
      for (int r = 1; r < 16; ++r) pmax = fmaxf(pmax, fmaxf(svA[r], svB[r]));
      pmax = fmaxf(pmax, __shfl_xor(pmax, 32));
      float smax = pmax * SCALE2;
      if (!__all(smax - m <= 8.0f)) {
        float mnew = fmaxf(m, smax);
        float a = exp2f(m - mnew);
        l *= a;
#pragma unroll
        for (int db = 0; db < 4; ++db)
#pragma unroll
          for (int r = 0; r < 16; ++r) oacc[db][r] *= a;
        m = mnew;
      }
      float eA[16], eB[16]; float sum = 0.f;
#pragma unroll
      for (int r = 0; r < 16; ++r) {
        eA[r] = exp2f(svA[r] * SCALE2 - m);
        eB[r] = exp2f(svB[r] * SCALE2 - m);
        sum += eA[r] + eB[r];
      }
      sum += __shfl_xor(sum, 32);
      l += sum;
      uint32_t pkA[8], pkB[8];
#pragma unroll
      for (int i = 0; i < 8; ++i) {
        pkA[i] = (uint32_t)f2bf(eA[2 * i]) | ((uint32_t)f2bf(eA[2 * i + 1]) << 16);
        pkB[i] = (uint32_t)f2bf(eB[2 * i]) | ((uint32_t)f2bf(eB[2 * i + 1]) << 16);
      }
      uint32_t swA[8], swB[8];
#pragma unroll
      for (int i = 0; i < 8; ++i) {
        swA[i] = (uint32_t)__shfl_xor((int)pkA[i], 32);
        swB[i] = (uint32_t)__shfl_xor((int)pkB[i], 32);
      }
      union { uint32_t u[4]; bf16x8 v; } pA0, pA1, pB0, pB1;
      pA0.u[0] = hi ? swA[2] : pkA[0];
      pA0.u[1] = hi ? swA[3] : pkA[1];
      pA0.u[2] = hi ? pkA[2] : swA[0];
      pA0.u[3] = hi ? pkA[3] : swA[1];
      pA1.u[0] = hi ? swA[6] : pkA[4];
      pA1.u[1] = hi ? swA[7] : pkA[5];
      pA1.u[2] = hi ? pkA[6] : swA[4];
      pA1.u[3] = hi ? pkA[7] : swA[5];
      pB0.u[0] = hi ? swB[2] : pkB[0];
      pB0.u[1] = hi ? swB[3] : pkB[1];
      pB0.u[2] = hi ? pkB[2] : swB[0];
      pB0.u[3] = hi ? pkB[3] : swB[1];
      pB1.u[0] = hi ? swB[6] : pkB[4];
      pB1.u[1] = hi ? swB[7] : pkB[5];
      pB1.u[2] = hi ? pkB[6] : swB[4];
      pB1.u[3] = hi ? pkB[7] : swB[5];
      __builtin_amdgcn_s_setprio(1);
#pragma unroll
      for (int db = 0; db < 4; ++db) {
        const int d = 32 * db + lq;
        const int vx = (d >> 3) & 7;
        const ushort* vr = Vs + d * 72;
        bf16x8 vf0 = *(const bf16x8*)(vr + (((0 + hi) ^ vx) << 3));
        bf16x8 vf1 = *(const bf16x8*)(vr + (((2 + hi) ^ vx) << 3));
        bf16x8 vf2 = *(const bf16x8*)(vr + (((4 + hi) ^ vx) << 3));
        bf16x8 vf3 = *(const bf16x8*)(vr + (((6 + hi) ^ vx) << 3));
        oacc[db] = __builtin_amdgcn_mfma_f32_32x32x16_bf16(vf0, pA0.v, oacc[db], 0, 0, 0);
        oacc[db] = __builtin_amdgcn_mfma_f32_32x32x16_bf16(vf1, pA1.v, oacc[db], 0, 0, 0);
        oacc[db] = __builtin_amdgcn_mfma_f32_32x32x16_bf16(vf2, pB0.v, oacc[db], 0, 0, 0);
        oacc[db] = __builtin_amdgcn_mfma_f32_32x32x16_bf16(vf3, pB1.v, oacc[db], 0, 0, 0);
      }
      __builtin_amdgcn_s_setprio(0);
    }
    asm volatile("s_waitcnt lgkmcnt(0)" ::: "memory");
    __syncthreads();
  }

  float inv = 1.f / l;
  ushort* op = aout + ((size_t)(b * 2048 + qg)) * 2048 + h * 128 + 4 * hi;
#pragma unroll
  for (int db = 0; db < 4; ++db)
#pragma unroll
    for (int i = 0; i < 8; ++i) {
      uint32_t u = (uint32_t)f2bf(oacc[db][2 * i] * inv) |
                   ((uint32_t)f2bf(oacc[db][2 * i + 1] * inv) << 16);
      int dbase = 32 * db + (i & 1) * 2 + (i >> 1) * 8;
      *(uint32_t*)(op + dbase) = u;
    }
}

// ---------------- launcher ----------------
extern "C" void kernel_launch(void* const* d_in, const int* in_sizes, int n_in,
                              void* d_out, int out_size, void* d_ws, size_t ws_size,
                              hipStream_t stream) {
  const float* x = (const float*)d_in[0];
  const float* fcos = (const float*)d_in[1];
  const float* fsin = (const float*)d_in[2];
  const float* wq_a = (const float*)d_in[3];
  const float* qnw = (const float*)d_in[4];
  const float* wq_b = (const float*)d_in[5];
  const float* wkv_a = (const float*)d_in[6];
  const float* kvnw = (const float*)d_in[7];
  const float* wkv_b = (const float*)d_in[8];
  const float* wo = (const float*)d_in[9];
  float* out = (float*)d_out;

  char* ws = (char*)d_ws;
  size_t off = 0;
  auto alloc = [&](size_t bytes) -> char* {
    char* p = ws + off;
    off += (bytes + 255) & ~(size_t)255;
    return p;
  };
  ushort* xb     = (ushort*)alloc(4096ull * 2048 * 2);
  ushort* wqkv_t = (ushort*)alloc(2176ull * 2048 * 2);   // rows 0-1535 wq_a^T, 1536-2111 wkv_a^T, rest pad
  ushort* wqb_t  = (ushort*)alloc(3072ull * 1536 * 2);
  ushort* wkvb_t = (ushort*)alloc(4096ull * 512 * 2);
  ushort* wo_t   = (ushort*)alloc(2048ull * 2048 * 2);
  ushort* cqkv   = (ushort*)alloc(4096ull * 2112 * 2);   // fused q_lora | kv_lora | k_pe (bf16)
  ushort* cqn    = (ushort*)alloc(4096ull * 1536 * 2);
  ushort* ckvn   = (ushort*)alloc(4096ull * 512 * 2);
  ushort* kbuf   = (ushort*)alloc(2ull * 16 * 2048 * 192 * 2);
  ushort* qbuf   = (ushort*)alloc(4096ull * 3072 * 2);   // q projection output
  ushort* aout   = xb;              // reuse: x dead after fused GEMM1
  ushort* vT     = wqkv_t;          // reuse: wqkv_t+wqb_t dead after GEMM2

  k_f32_to_bf16<<<2048, 256, 0, stream>>>(x, xb, 4096 * 2048 / 4);
  // merged transposes: wq_a|wkv_a -> wqkv_t (fused), wq_b, wkv_b, wo
  k_transpose_all<<<14976, dim3(32, 8), 0, stream>>>(
      wq_a, wkv_a, wq_b, wkv_b, wo,
      wqkv_t, wqkv_t + 1536ull * 2048, wqb_t, wkvb_t, wo_t);

  // fused GEMM1: cqkv = xb @ [wq_a | wkv_a]  (M=4096, K=2048, Nreal=2112), bf16 out
  k_gemm<ushort><<<dim3(17, 32), 256, 0, stream>>>(xb, wqkv_t, cqkv, 2048, 2112);

  k_rmsnorm_bf16<<<4096, 256, 0, stream>>>(cqkv, qnw, cqn, 1536, 2112);
  k_kvnorm_rope<<<4096, 256, 0, stream>>>(cqkv, kvnw, fcos, fsin, ckvn, kbuf);

  // q = cqn @ wq_b (K=1536, N=3072), bf16 out with FUSED RoPE epilogue
  k_gemm_qrope<<<dim3(24, 32), 256, 0, stream>>>(cqn, wqb_t, qbuf, 1536, fcos, fsin);

  // kv = ckvn @ wkv_b (K=512, N=4096) -> kbuf + vT (scatter epilogue)
  k_gemm_kv<<<dim3(32, 32), 256, 0, stream>>>(ckvn, wkvb_t, kbuf, vT, 512);

  k_attn10<<<dim3(512), 256, 0, stream>>>(qbuf, kbuf, vT, aout);

  // out = aout @ wo (K=2048, N=2048), fp32 out
  k_gemm<float><<<dim3(16, 32), 256, 0, stream>>>(aout, wo_t, out, 2048, 2048);
}